// Round 15
// baseline (290.937 us; speedup 1.0000x reference)
//
#include <hip/hip_runtime.h>
#include <hip/hip_bf16.h>
#include <stdint.h>

typedef float f32x4 __attribute__((ext_vector_type(4)));
typedef short s16x8 __attribute__((ext_vector_type(8)));
typedef short s16x4 __attribute__((ext_vector_type(4)));

__device__ __forceinline__ short f2bf(float x) {
    union { float f; uint32_t u; } v; v.f = x;
    uint32_t r = v.u + 0x7fffu + ((v.u >> 16) & 1u);
    return (short)(r >> 16);
}
__device__ __forceinline__ float bf2f(short b) {
    union { uint32_t u; float f; } v; v.u = ((uint32_t)(uint16_t)b) << 16;
    return v.f;
}
__device__ __forceinline__ void gld16(const void* g, void* l) {
    __builtin_amdgcn_global_load_lds((const __attribute__((address_space(1))) uint32_t*)g,
                                     (__attribute__((address_space(3))) uint32_t*)l, 16, 0, 0);
}

// ---- cvt ALL weights -> bf16 (q|k|v, o, sg|su, sd, gu, wd) ----
__global__ __launch_bounds__(256) void cvt_all_kernel(const float* __restrict__ q, const float* __restrict__ k,
                                                      const float* __restrict__ v, const float* __restrict__ o,
                                                      const float* __restrict__ sg, const float* __restrict__ su,
                                                      const float* __restrict__ sd, const float* __restrict__ gu,
                                                      const float* __restrict__ wd, short* __restrict__ wqkv,
                                                      short* __restrict__ wo, short* __restrict__ wsgsu,
                                                      short* __restrict__ wsd, short* __restrict__ wgu,
                                                      short* __restrict__ wdB) {
    size_t i = (size_t)blockIdx.x * 256 + threadIdx.x;  // f32x8 chunk; grid covers exactly 3866624
    const float* src; short* dst;
    if (i < 196608) {
        if (i < 131072) { src = q + i * 8; dst = wqkv + i * 8; }
        else if (i < 163840) { src = k + (i - 131072) * 8; dst = wqkv + 1048576 + (i - 131072) * 8; }
        else { src = v + (i - 163840) * 8; dst = wqkv + 1310720 + (i - 163840) * 8; }
    } else if (i < 720896) {
        if (i < 327680) { src = o + (i - 196608) * 8; dst = wo + (i - 196608) * 8; }
        else if (i < 458752) { src = sg + (i - 327680) * 8; dst = wsgsu + (i - 327680) * 8; }
        else if (i < 589824) { src = su + (i - 458752) * 8; dst = wsgsu + 1048576 + (i - 458752) * 8; }
        else { src = sd + (i - 589824) * 8; dst = wsd + (i - 589824) * 8; }
    } else {
        if (i < 2818048) { src = gu + (i - 720896) * 8; dst = wgu + (i - 720896) * 8; }
        else { src = wd + (i - 2818048) * 8; dst = wdB + (i - 2818048) * 8; }
    }
    f32x4 a = ((const f32x4*)src)[0];
    f32x4 b = ((const f32x4*)src)[1];
    s16x8 o8;
    o8[0] = f2bf(a[0]); o8[1] = f2bf(a[1]); o8[2] = f2bf(a[2]); o8[3] = f2bf(a[3]);
    o8[4] = f2bf(b[0]); o8[5] = f2bf(b[1]); o8[6] = f2bf(b[2]); o8[7] = f2bf(b[3]);
    *(s16x8*)dst = o8;
}

// ---------------- RMSNorm (row=1024), writes bf16 ----------------
__global__ __launch_bounds__(256) void rmsnorm_kernel(const float* __restrict__ x, const float* __restrict__ w,
                                                      short* __restrict__ out) {
    int t = blockIdx.x;
    f32x4 v = ((const f32x4*)(x + (size_t)t * 1024))[threadIdx.x];
    float ssq = v[0]*v[0] + v[1]*v[1] + v[2]*v[2] + v[3]*v[3];
#pragma unroll
    for (int o = 1; o < 64; o <<= 1) ssq += __shfl_xor(ssq, o);
    __shared__ float red[4];
    if ((threadIdx.x & 63) == 0) red[threadIdx.x >> 6] = ssq;
    __syncthreads();
    float tot = red[0] + red[1] + red[2] + red[3];
    float rs = rsqrtf(tot * (1.0f / 1024.0f) + 1e-6f);
    f32x4 wv = ((const f32x4*)w)[threadIdx.x];
    s16x4 o4;
#pragma unroll
    for (int j = 0; j < 4; ++j) o4[j] = f2bf(v[j] * rs * wv[j]);
    ((s16x4*)(out + (size_t)t * 1024))[threadIdx.x] = o4;
}

// ---- residual add + RMSNorm; b = 4 bf16 split-K slices; writes res f32, xf bf16, xf32 f32 ----
__global__ __launch_bounds__(256) void addnorm_kernel(const float* __restrict__ a, const short* __restrict__ b,
                                                      const float* __restrict__ w, float* __restrict__ res,
                                                      short* __restrict__ xf, float* __restrict__ xf32) {
    int t = blockIdx.x;
    f32x4 va = ((const f32x4*)(a + (size_t)t * 1024))[threadIdx.x];
    f32x4 vb = {0.f, 0.f, 0.f, 0.f};
#pragma unroll
    for (int z = 0; z < 4; ++z) {
        s16x4 dz = *(const s16x4*)(b + (size_t)z * 2048 * 1024 + (size_t)t * 1024 + threadIdx.x * 4);
#pragma unroll
        for (int j = 0; j < 4; ++j) vb[j] += bf2f(dz[j]);
    }
    f32x4 s = va + vb;
    ((f32x4*)(res + (size_t)t * 1024))[threadIdx.x] = s;
    float ssq = s[0]*s[0] + s[1]*s[1] + s[2]*s[2] + s[3]*s[3];
#pragma unroll
    for (int o = 1; o < 64; o <<= 1) ssq += __shfl_xor(ssq, o);
    __shared__ float red[4];
    if ((threadIdx.x & 63) == 0) red[threadIdx.x >> 6] = ssq;
    __syncthreads();
    float tot = red[0] + red[1] + red[2] + red[3];
    float rs = rsqrtf(tot * (1.0f / 1024.0f) + 1e-6f);
    f32x4 wv = ((const f32x4*)w)[threadIdx.x];
    f32x4 xo;
    s16x4 o4;
#pragma unroll
    for (int j = 0; j < 4; ++j) { xo[j] = s[j] * rs * wv[j]; o4[j] = f2bf(xo[j]); }
    ((f32x4*)(xf32 + (size_t)t * 1024))[threadIdx.x] = xo;
    ((s16x4*)(xf + (size_t)t * 1024))[threadIdx.x] = o4;
}

// ==== GEMM (bf16 B): 128x128, BK=32, gld16 both operands, optional plan/worklist mode ====
// dense: grid(x=M/128, y=N/128, z=ksplit). moe (plan!=null): grid(x=N/128, y=planmax, z=ksplit),
// plan entry = e | m<<5 (128-row units); A rows via lists (pair >> a_shift), C row = pair.
__global__ __launch_bounds__(256, 4) void gemm2_kernel(const short* __restrict__ A, const short* __restrict__ Bg,
                                                       void* __restrict__ Cv, int M, int N, int Ktot, int Ksub,
                                                       long long cstride,
                                                       const int* __restrict__ counts, const int* __restrict__ lists,
                                                       const int* __restrict__ plan, int a_shift, int store_bf16) {
    __shared__ short As[2][128 * 32];
    __shared__ short Bs[2][128 * 32];
    int e, bm, bn, Mloc;
    size_t coff = (size_t)blockIdx.z * cstride;
    const int* rl = nullptr;
    if (plan) {
        int wi = blockIdx.y;
        if (wi >= plan[0]) return;
        int it = plan[1 + wi];
        e = it & 31; bm = (it >> 5) * 128;
        bn = blockIdx.x * 128;
        Mloc = counts[e]; rl = lists + e * 2048;
    } else {
        e = 0; bm = blockIdx.x * 128; bn = blockIdx.y * 128;
        Mloc = M;
    }
    int k0 = blockIdx.z * Ksub;
    if (bm >= Mloc) return;
    const short* Bt = Bg + (size_t)e * N * Ktot;
    int tid = threadIdx.x, w = tid >> 6, l = tid & 63;
    int lr = l & 15, lg = l >> 4;
    int rsub = l >> 2, u = l & 3;
    int fs = (rsub & 3) ^ ((rsub >> 2) & 3);
    int colsel = (u ^ fs) * 8;
    int ra = w * 32 + rsub;
    int ga0 = bm + ra;       if (ga0 > Mloc - 1) ga0 = Mloc - 1;
    int ga1 = bm + ra + 16;  if (ga1 > Mloc - 1) ga1 = Mloc - 1;
    int ar0 = rl ? (rl[ga0] >> a_shift) : ga0;
    int ar1 = rl ? (rl[ga1] >> a_shift) : ga1;
    const short* Ap0 = A + (size_t)ar0 * Ktot + k0 + colsel;
    const short* Ap1 = A + (size_t)ar1 * Ktot + k0 + colsel;
    const short* Bp0 = Bt + (size_t)(bn + ra) * Ktot + k0 + colsel;
    const short* Bp1 = Bt + (size_t)(bn + ra + 16) * Ktot + k0 + colsel;
    int lb0 = w * 1024, lb1 = w * 1024 + 512;

    int wm = (w >> 1) * 64, wn = (w & 1) * 64;
    int su = lg ^ (lr & 3) ^ ((lr >> 2) & 3);
    int aoff[4], boff[4];
#pragma unroll
    for (int mf = 0; mf < 4; ++mf) aoff[mf] = (wm + mf * 16 + lr) * 32 + su * 8;
#pragma unroll
    for (int nf = 0; nf < 4; ++nf) boff[nf] = (wn + nf * 16 + lr) * 32 + su * 8;

    f32x4 zero4 = {0.f, 0.f, 0.f, 0.f};
    f32x4 acc[4][4];
#pragma unroll
    for (int mf = 0; mf < 4; ++mf)
#pragma unroll
        for (int nf = 0; nf < 4; ++nf) acc[mf][nf] = zero4;

#define STAGE(buf, kt) do { \
        gld16(Ap0 + (kt) * 32, &As[buf][lb0]); \
        gld16(Ap1 + (kt) * 32, &As[buf][lb1]); \
        gld16(Bp0 + (kt) * 32, &Bs[buf][lb0]); \
        gld16(Bp1 + (kt) * 32, &Bs[buf][lb1]); \
    } while (0)

    int nk = Ksub >> 5;
    STAGE(0, 0);
    asm volatile("s_waitcnt vmcnt(0)");
    __syncthreads();
    for (int kt = 0; kt < nk; ++kt) {
        int cur = kt & 1;
        if (kt + 1 < nk) STAGE(cur ^ 1, kt + 1);
        s16x8 af[4], bfr[4];
#pragma unroll
        for (int mf = 0; mf < 4; ++mf) af[mf] = *(const s16x8*)&As[cur][aoff[mf]];
#pragma unroll
        for (int nf = 0; nf < 4; ++nf) bfr[nf] = *(const s16x8*)&Bs[cur][boff[nf]];
#pragma unroll
        for (int mf = 0; mf < 4; ++mf)
#pragma unroll
            for (int nf = 0; nf < 4; ++nf)
                acc[mf][nf] = __builtin_amdgcn_mfma_f32_16x16x32_bf16(af[mf], bfr[nf], acc[mf][nf], 0, 0, 0);
        __syncthreads();
    }
#undef STAGE
    float* Cf = (float*)Cv;
    short* Cs = (short*)Cv;
#pragma unroll
    for (int mf = 0; mf < 4; ++mf) {
        int rbase = bm + wm + mf * 16 + lg * 4;
#pragma unroll
        for (int r = 0; r < 4; ++r) {
            int grow = rbase + r;
            if (grow < Mloc) {
                int crow = rl ? rl[grow] : grow;
                size_t cb = coff + (size_t)crow * N + bn + wn + lr;
                if (store_bf16) {
#pragma unroll
                    for (int nf = 0; nf < 4; ++nf) Cs[cb + nf * 16] = f2bf(acc[mf][nf][r]);
                } else {
#pragma unroll
                    for (int nf = 0; nf < 4; ++nf) Cf[cb + nf * 16] = acc[mf][nf][r];
                }
            }
        }
    }
}

// ---- RoPE; input qkv = 4 bf16 split-K slices [4][2048][1536]; out Qr*0.125, Kr, Vt[B,4,64,S] ----
__global__ __launch_bounds__(64) void rope_kernel(const short* __restrict__ qkv, short* __restrict__ Qr,
                                                  short* __restrict__ Kr, short* __restrict__ Vt) {
    int t = blockIdx.x;
    int b = t >> 10, s = t & 1023;
    int l = threadIdx.x;
    __shared__ float cs[32], sn[32], row[1536];
    float acc[24];
#pragma unroll
    for (int c = 0; c < 24; ++c) acc[c] = 0.f;
#pragma unroll
    for (int z = 0; z < 4; ++z) {
        const short* src = qkv + (size_t)z * 2048 * 1536 + (size_t)t * 1536 + l * 24;
#pragma unroll
        for (int c8 = 0; c8 < 3; ++c8) {
            s16x8 v8 = *(const s16x8*)(src + c8 * 8);
#pragma unroll
            for (int j = 0; j < 8; ++j) acc[c8 * 8 + j] += bf2f(v8[j]);
        }
    }
#pragma unroll
    for (int c = 0; c < 24; ++c) row[l * 24 + c] = acc[c];
    if (l < 32) {
        float fr = (float)t * exp2f(-(float)l * 0.41524101186f);
        cs[l] = cosf(fr); sn[l] = sinf(fr);
    }
    __syncthreads();
    int d = l;
    float c = cs[d & 31], sv = sn[d & 31];
#pragma unroll
    for (int h = 0; h < 16; ++h) {
        float x = row[h * 64 + d];
        float rot = (d < 32) ? -row[h * 64 + d + 32] : row[h * 64 + d - 32];
        Qr[((size_t)(b * 16 + h) * 1024 + s) * 64 + d] = f2bf((x * c + rot * sv) * 0.125f);
    }
#pragma unroll
    for (int h = 0; h < 4; ++h) {
        float x = row[1024 + h * 64 + d];
        float rot = (d < 32) ? -row[1024 + h * 64 + d + 32] : row[1024 + h * 64 + d - 32];
        Kr[((size_t)(b * 4 + h) * 1024 + s) * 64 + d] = f2bf(x * c + rot * sv);
        Vt[((size_t)(b * 4 + h) * 64 + d) * 1024 + s] = f2bf(row[1280 + h * 64 + d]);
    }
}

// ---------------- flash attention v2: paired q-tiles + K/V register prefetch ----------------
struct KV { s16x8 k[4]; s16x8 v[4]; };
__device__ __forceinline__ void kv_load(KV& r, const short* Kb, const short* Vb, int k0, int lr, int lg) {
    const short* K0 = Kb + (size_t)(k0 + lr) * 64 + lg * 8;
    const short* K1 = Kb + (size_t)(k0 + 16 + lr) * 64 + lg * 8;
    r.k[0] = *(const s16x8*)K0;
    r.k[1] = *(const s16x8*)(K0 + 32);
    r.k[2] = *(const s16x8*)K1;
    r.k[3] = *(const s16x8*)(K1 + 32);
#pragma unroll
    for (int dt = 0; dt < 4; ++dt)
        r.v[dt] = *(const s16x8*)(Vb + (size_t)(dt * 16 + lr) * 1024 + k0 + lg * 8);
}
__device__ __forceinline__ void chain_step(const KV& kv, s16x8 qf0, s16x8 qf1, f32x4* o,
                                           float& m, float& lsum, short* Pl,
                                           int lr, int lg, int k0, int qmask) {
    f32x4 z = {0.f, 0.f, 0.f, 0.f};
    f32x4 sc0 = z, sc1 = z;
    sc0 = __builtin_amdgcn_mfma_f32_16x16x32_bf16(kv.k[0], qf0, sc0, 0, 0, 0);
    sc0 = __builtin_amdgcn_mfma_f32_16x16x32_bf16(kv.k[1], qf1, sc0, 0, 0, 0);
    sc1 = __builtin_amdgcn_mfma_f32_16x16x32_bf16(kv.k[2], qf0, sc1, 0, 0, 0);
    sc1 = __builtin_amdgcn_mfma_f32_16x16x32_bf16(kv.k[3], qf1, sc1, 0, 0, 0);
#pragma unroll
    for (int r = 0; r < 4; ++r) {
        if (k0 + lg * 4 + r > qmask) sc0[r] = -1e30f;
        if (k0 + 16 + lg * 4 + r > qmask) sc1[r] = -1e30f;
    }
    float tm = fmaxf(fmaxf(fmaxf(sc0[0], sc0[1]), fmaxf(sc0[2], sc0[3])),
                     fmaxf(fmaxf(sc1[0], sc1[1]), fmaxf(sc1[2], sc1[3])));
    tm = fmaxf(tm, __shfl_xor(tm, 16));
    tm = fmaxf(tm, __shfl_xor(tm, 32));
    float newm = fmaxf(m, tm);
    float fac = __expf(m - newm);
    float p[8];
#pragma unroll
    for (int r = 0; r < 4; ++r) { p[r] = __expf(sc0[r] - newm); p[4 + r] = __expf(sc1[r] - newm); }
    float ts = ((p[0] + p[1]) + (p[2] + p[3])) + ((p[4] + p[5]) + (p[6] + p[7]));
    ts += __shfl_xor(ts, 16);
    ts += __shfl_xor(ts, 32);
    lsum = lsum * fac + ts;
    m = newm;
    s16x4 w0, w1;
#pragma unroll
    for (int r = 0; r < 4; ++r) { w0[r] = f2bf(p[r]); w1[r] = f2bf(p[4 + r]); }
    *(s16x4*)&Pl[lr * 40 + lg * 4] = w0;
    *(s16x4*)&Pl[lr * 40 + 16 + lg * 4] = w1;
    s16x8 pf = *(const s16x8*)&Pl[lr * 40 + lg * 8];
#pragma unroll
    for (int dt = 0; dt < 4; ++dt) {
        o[dt] *= fac;
        o[dt] = __builtin_amdgcn_mfma_f32_16x16x32_bf16(kv.v[dt], pf, o[dt], 0, 0, 0);
    }
}

__global__ __launch_bounds__(64) void attn_kernel(const short* __restrict__ Qr, const short* __restrict__ Kr,
                                                  const short* __restrict__ Vt, short* __restrict__ attn_out) {
    int p = blockIdx.x;
    int hb = blockIdx.y;
    int b = hb >> 4, h = hb & 15, kv = h >> 2;
    int l = threadIdx.x;
    int lr = l & 15, lg = l >> 4;
    int q0A = p * 16, q0B = (63 - p) * 16;
    __shared__ short PlA[16 * 40], PlB[16 * 40];
    const short* Qh = Qr + (size_t)(b * 16 + h) * 1024 * 64;
    s16x8 qA0 = *(const s16x8*)(Qh + (size_t)(q0A + lr) * 64 + lg * 8);
    s16x8 qA1 = *(const s16x8*)(Qh + (size_t)(q0A + lr) * 64 + 32 + lg * 8);
    s16x8 qB0 = *(const s16x8*)(Qh + (size_t)(q0B + lr) * 64 + lg * 8);
    s16x8 qB1 = *(const s16x8*)(Qh + (size_t)(q0B + lr) * 64 + 32 + lg * 8);
    const short* Kbase = Kr + (size_t)(b * 4 + kv) * 1024 * 64;
    const short* Vbase = Vt + (size_t)(b * 4 + kv) * 64 * 1024;

    f32x4 zero4 = {0.f, 0.f, 0.f, 0.f};
    f32x4 oA[4], oB[4];
#pragma unroll
    for (int dt = 0; dt < 4; ++dt) { oA[dt] = zero4; oB[dt] = zero4; }
    float mA = -1e30f, lsA = 0.f, mB = -1e30f, lsB = 0.f;
    int ntA = (q0A + 47) >> 5, ntB = (q0B + 47) >> 5;
    int qmA = q0A + lr, qmB = q0B + lr;
    const int BIG = 1 << 29;

    KV b0, b1;
    kv_load(b0, Kbase, Vbase, 0, lr, lg);
    for (int kt = 0; kt < ntB; kt += 2) {
        if (kt + 1 < ntB) kv_load(b1, Kbase, Vbase, (kt + 1) * 32, lr, lg);
        if (kt < ntA) chain_step(b0, qA0, qA1, oA, mA, lsA, PlA, lr, lg, kt * 32,
                                 (kt == ntA - 1) ? qmA : BIG);
        chain_step(b0, qB0, qB1, oB, mB, lsB, PlB, lr, lg, kt * 32,
                   (kt == ntB - 1) ? qmB : BIG);
        if (kt + 1 >= ntB) break;
        if (kt + 2 < ntB) kv_load(b0, Kbase, Vbase, (kt + 2) * 32, lr, lg);
        if (kt + 1 < ntA) chain_step(b1, qA0, qA1, oA, mA, lsA, PlA, lr, lg, (kt + 1) * 32,
                                     (kt + 1 == ntA - 1) ? qmA : BIG);
        chain_step(b1, qB0, qB1, oB, mB, lsB, PlB, lr, lg, (kt + 1) * 32,
                   (kt + 1 == ntB - 1) ? qmB : BIG);
    }
    float invA = 1.f / lsA, invB = 1.f / lsB;
    short* oa = attn_out + ((size_t)(b * 1024 + q0A + lr)) * 1024 + h * 64;
    short* ob = attn_out + ((size_t)(b * 1024 + q0B + lr)) * 1024 + h * 64;
#pragma unroll
    for (int dt = 0; dt < 4; ++dt)
#pragma unroll
        for (int r = 0; r < 4; ++r) {
            oa[dt * 16 + lg * 4 + r] = f2bf(oA[dt][r] * invA);
            ob[dt * 16 + lg * 4 + r] = f2bf(oB[dt][r] * invB);
        }
}

// ---------------- router R1: logits + top-k per token (no atomics) ----------------
__global__ __launch_bounds__(256) void router_topk_kernel(const float* __restrict__ x32, const float* __restrict__ gw,
                                                          const float* __restrict__ eb, float* __restrict__ tw,
                                                          int* __restrict__ tidx) {
    int t = blockIdx.x * 4 + (threadIdx.x >> 6);
    int l = threadIdx.x & 63;
    const float* x = x32 + (size_t)t * 1024;
    f32x4 xv[4];
#pragma unroll
    for (int j = 0; j < 4; ++j) xv[j] = *(const f32x4*)(x + j * 256 + l * 4);
    float acc[16];
#pragma unroll
    for (int e = 0; e < 16; ++e) {
        float a = 0.f;
#pragma unroll
        for (int j = 0; j < 4; ++j) {
            f32x4 g = *(const f32x4*)(gw + (size_t)e * 1024 + j * 256 + l * 4);
            a += xv[j][0]*g[0] + xv[j][1]*g[1] + xv[j][2]*g[2] + xv[j][3]*g[3];
        }
        acc[e] = a;
    }
#pragma unroll
    for (int e = 0; e < 16; ++e) {
#pragma unroll
        for (int o = 1; o < 64; o <<= 1) acc[e] += __shfl_xor(acc[e], o);
    }
    if (l == 0) {
        float score[16], sfc[16];
#pragma unroll
        for (int e = 0; e < 16; ++e) {
            score[e] = 1.f / (1.f + __expf(-acc[e]));
            sfc[e] = score[e] + eb[e];
        }
        float gs[4];
#pragma unroll
        for (int g = 0; g < 4; ++g)
            gs[g] = fmaxf(fmaxf(sfc[4 * g], sfc[4 * g + 1]), fmaxf(sfc[4 * g + 2], sfc[4 * g + 3]));
        int g1 = 0;
        for (int g = 1; g < 4; ++g) if (gs[g] > gs[g1]) g1 = g;
        int g2 = -1;
        for (int g = 0; g < 4; ++g) {
            if (g == g1) continue;
            if (g2 < 0 || gs[g] > gs[g2]) g2 = g;
        }
        float masked[16];
#pragma unroll
        for (int e = 0; e < 16; ++e) {
            int g = e >> 2;
            masked[e] = (g == g1 || g == g2) ? sfc[e] : 0.0f;
        }
        float tot = 1e-20f;
        int idx[4]; float wv[4];
        for (int k = 0; k < 4; ++k) {
            int bi = 0;
            float bv = -1e30f;
            for (int e2 = 0; e2 < 16; ++e2)
                if (masked[e2] > bv) { bv = masked[e2]; bi = e2; }
            idx[k] = bi;
            wv[k] = score[bi];
            masked[bi] = -1e30f;
            tot += wv[k];
        }
        for (int k = 0; k < 4; ++k) {
            tw[t * 4 + k] = wv[k] / tot * 2.5f;
            tidx[t * 4 + k] = idx[k];
        }
    }
}

// ---------------- router R2: per-expert ordered compaction (1 wave per expert) ----------------
__global__ __launch_bounds__(64) void router_lists_kernel(const int* __restrict__ tidx, int* __restrict__ counts,
                                                          int* __restrict__ lists) {
    int e = blockIdx.x;
    int l = threadIdx.x;
    int base = 0;
    for (int it = 0; it < 128; ++it) {
        int p = it * 64 + l;
        bool match = (tidx[p] == e);
        unsigned long long mask = __ballot(match);
        int pos = __popcll(mask & ((1ull << l) - 1ull));
        if (match) lists[e * 2048 + base + pos] = p;
        base += __popcll(mask);
    }
    if (l == 0) counts[e] = base;
}

// ---- build (expert, mblock) work list: plan[0]=count, plan[1+i] = e | (m<<5) ----
__global__ void plan_kernel(const int* __restrict__ counts, int* __restrict__ plan) {
    if (threadIdx.x == 0) {
        int n = 0;
        for (int e = 0; e < 16; ++e) {
            int nb = (counts[e] + 127) >> 7;
            for (int m2 = 0; m2 < nb; ++m2) plan[1 + n++] = e | (m2 << 5);
        }
        plan[0] = n;
    }
}

// ---- silu-mul routed: gu 2 bf16 slices [2][8192][1024] -> hid[p][512] bf16 ----
__global__ __launch_bounds__(128) void silu_routed_kernel(const short* __restrict__ gu, short* __restrict__ hid) {
    int pr = blockIdx.x;
    int j = threadIdx.x * 4;
    float g[4] = {0.f, 0.f, 0.f, 0.f}, u2[4] = {0.f, 0.f, 0.f, 0.f};
#pragma unroll
    for (int z = 0; z < 2; ++z) {
        const short* base = gu + (size_t)z * 8192 * 1024 + (size_t)pr * 1024;
        s16x4 gz = *(const s16x4*)(base + j);
        s16x4 uz = *(const s16x4*)(base + 512 + j);
#pragma unroll
        for (int k = 0; k < 4; ++k) { g[k] += bf2f(gz[k]); u2[k] += bf2f(uz[k]); }
    }
    s16x4 o;
#pragma unroll
    for (int k = 0; k < 4; ++k) o[k] = f2bf(g[k] / (1.f + __expf(-g[k])) * u2[k]);
    *(s16x4*)(hid + (size_t)pr * 512 + j) = o;
}

// ---- silu-mul shared: sgsu 2 bf16 slices [2][2048][2048] -> shhid[t][1024] bf16 ----
__global__ __launch_bounds__(256) void silu_shared_kernel(const short* __restrict__ gu, short* __restrict__ h) {
    int t = blockIdx.x;
    int j = threadIdx.x * 4;
    float g[4] = {0.f, 0.f, 0.f, 0.f}, u2[4] = {0.f, 0.f, 0.f, 0.f};
#pragma unroll
    for (int z = 0; z < 2; ++z) {
        const short* base = gu + (size_t)z * 2048 * 2048 + (size_t)t * 2048;
        s16x4 gz = *(const s16x4*)(base + j);
        s16x4 uz = *(const s16x4*)(base + 1024 + j);
#pragma unroll
        for (int k = 0; k < 4; ++k) { g[k] += bf2f(gz[k]); u2[k] += bf2f(uz[k]); }
    }
    s16x4 o;
#pragma unroll
    for (int k = 0; k < 4; ++k) o[k] = f2bf(g[k] / (1.f + __expf(-g[k])) * u2[k]);
    *(s16x4*)(h + (size_t)t * 1024 + j) = o;
}

// ---- combine: out = res2 + sum_z sd[z] + sum_s w_s * down[t*4+s] ----
__global__ __launch_bounds__(256) void combine_kernel(const float* __restrict__ res2, const short* __restrict__ sdp,
                                                      const short* __restrict__ slots, const float* __restrict__ tw,
                                                      float* __restrict__ out) {
    int t = blockIdx.x;
    int i = threadIdx.x;
    f32x4 acc = ((const f32x4*)(res2 + (size_t)t * 1024))[i];
#pragma unroll
    for (int z = 0; z < 4; ++z) {
        s16x4 d = *(const s16x4*)(sdp + (size_t)z * 2048 * 1024 + (size_t)t * 1024 + i * 4);
#pragma unroll
        for (int j = 0; j < 4; ++j) acc[j] += bf2f(d[j]);
    }
#pragma unroll
    for (int s = 0; s < 4; ++s) {
        float w = tw[t * 4 + s];
        s16x4 d = ((const s16x4*)(slots + (size_t)(t * 4 + s) * 1024))[i];
#pragma unroll
        for (int j = 0; j < 4; ++j) acc[j] += bf2f(d[j]) * w;
    }
    ((f32x4*)(out + (size_t)t * 1024))[i] = acc;
}

extern "C" void kernel_launch(void* const* d_in, const int* in_sizes, int n_in,
                              void* d_out, int out_size, void* d_ws, size_t ws_size,
                              hipStream_t stream) {
    const float* hidden = (const float*)d_in[0];
    const float* ln1 = (const float*)d_in[2];
    const float* ln2 = (const float*)d_in[3];
    const float* qw = (const float*)d_in[4];
    const float* kw = (const float*)d_in[5];
    const float* vw = (const float*)d_in[6];
    const float* ow = (const float*)d_in[7];
    const float* gatew = (const float*)d_in[8];
    const float* ebias = (const float*)d_in[9];
    const float* wgu = (const float*)d_in[10];
    const float* wd = (const float*)d_in[11];
    const float* sgw = (const float*)d_in[12];
    const float* suw = (const float*)d_in[13];
    const float* sdw = (const float*)d_in[14];
    float* out = (float*)d_out;

    char* base = (char*)d_ws;
    size_t off = 0;
    auto alloc = [&](size_t bytes) -> char* {
        char* r = base + off;
        off += (bytes + 255) & ~(size_t)255;
        return r;
    };
    const size_t MB = 1u << 20;

    // ---- persistent weights (bf16: all)
    short* wqkv_b = (short*)alloc((size_t)1536 * 1024 * 2);
    short* wsgsu_b= (short*)alloc((size_t)2048 * 1024 * 2);
    short* wo_b   = (short*)alloc((size_t)1024 * 1024 * 2);
    short* wsd_b  = (short*)alloc((size_t)1024 * 1024 * 2);
    short* wgu_b  = (short*)alloc((size_t)16 * 1024 * 1024 * 2);
    short* wd_b   = (short*)alloc((size_t)16 * 1024 * 512 * 2);
    // ---- persistent activations / routing
    float* res2 = (float*)alloc((size_t)2048 * 1024 * 4);
    short* xf   = (short*)alloc((size_t)2048 * 1024 * 2);
    float* topkw = (float*)alloc(2048 * 4 * 4);
    int* tidx   = (int*)alloc(8192 * 4);
    int* counts = (int*)alloc(64);
    int* lists  = (int*)alloc(16 * 2048 * 4);
    int* plan   = (int*)alloc(512);
    short* shhid = (short*)alloc((size_t)2048 * 1024 * 2);
    short* hid   = (short*)alloc((size_t)8192 * 512 * 2);

    // ---- overlay region (50 MiB), sequential phases
    char* ov = alloc(50 * MB);
    short* xn1       = (short*)(ov);                 // 4 MB
    short* qkv_part  = (short*)(ov + 4 * MB);        // 4 slices x 6 MB = 24 MB
    short* Qr        = (short*)(ov);                 // 4 MB (xn1 dead)
    short* Kr        = (short*)(ov + 28 * MB);       // 1 MB
    short* Vt        = (short*)(ov + 29 * MB);       // 1 MB
    short* attn_out  = (short*)(ov + 30 * MB);       // 4 MB
    short* attnproj_part = (short*)(ov + 34 * MB);   // 4 slices x 4 MB = 16 MB
    float* xf32      = (float*)(ov);                 // 8 MB (Qr dead after attn)
    short* upbuf     = (short*)(ov);                 // 32 MB: sgsu 2x8MB, then gu 2x16MB
    short* down_slot = (short*)(ov);                 // 16 MB (upbuf dead after silu_routed)
    short* sd_part   = (short*)(ov + 16 * MB);       // 4 slices x 4 MB = 16 MB

    // ---- weight conversion (all weights -> bf16)
    cvt_all_kernel<<<15104, 256, 0, stream>>>(qw, kw, vw, ow, sgw, suw, sdw, wgu, wd,
                                              wqkv_b, wo_b, wsgsu_b, wsd_b, wgu_b, wd_b);

    // ---- attention block
    rmsnorm_kernel<<<2048, 256, 0, stream>>>(hidden, ln1, xn1);
    gemm2_kernel<<<dim3(16, 12, 4), 256, 0, stream>>>(xn1, wqkv_b, qkv_part, 2048, 1536, 1024, 256,
                                                      2048LL * 1536, nullptr, nullptr, nullptr, 0, 1);
    rope_kernel<<<2048, 64, 0, stream>>>(qkv_part, Qr, Kr, Vt);
    attn_kernel<<<dim3(32, 32, 1), 64, 0, stream>>>(Qr, Kr, Vt, attn_out);
    gemm2_kernel<<<dim3(16, 8, 4), 256, 0, stream>>>(attn_out, wo_b, attnproj_part, 2048, 1024, 1024, 256,
                                                     2048LL * 1024, nullptr, nullptr, nullptr, 0, 1);
    addnorm_kernel<<<2048, 256, 0, stream>>>(hidden, attnproj_part, ln2, res2, xf, xf32);

    // ---- router (atomic-free) + plan
    router_topk_kernel<<<512, 256, 0, stream>>>(xf32, gatew, ebias, topkw, tidx);
    router_lists_kernel<<<16, 64, 0, stream>>>(tidx, counts, lists);
    plan_kernel<<<1, 64, 0, stream>>>(counts, plan);

    // ---- shared expert up (sg|su fused bf16 B, split-K 2) + silu
    gemm2_kernel<<<dim3(16, 16, 2), 256, 0, stream>>>(xf, wsgsu_b, upbuf, 2048, 2048, 1024, 512,
                                                      2048LL * 2048, nullptr, nullptr, nullptr, 0, 1);
    silu_shared_kernel<<<2048, 256, 0, stream>>>(upbuf, shhid);

    // ---- routed experts up (bf16 B, plan-mode, split-K 2) + silu
    gemm2_kernel<<<dim3(8, 80, 2), 256, 0, stream>>>(xf, wgu_b, upbuf, 0, 1024, 1024, 512,
                                                     8192LL * 1024, counts, lists, plan, 2, 1);
    silu_routed_kernel<<<8192, 128, 0, stream>>>(upbuf, hid);

    // ---- down projections (bf16 B)
    gemm2_kernel<<<dim3(8, 80, 1), 256, 0, stream>>>(hid, wd_b, down_slot, 0, 1024, 512, 512,
                                                     0LL, counts, lists, plan, 0, 1);
    gemm2_kernel<<<dim3(16, 8, 4), 256, 0, stream>>>(shhid, wsd_b, sd_part, 2048, 1024, 1024, 256,
                                                     2048LL * 1024, nullptr, nullptr, nullptr, 0, 1);

    // ---- combine
    combine_kernel<<<2048, 256, 0, stream>>>(res2, sd_part, down_slot, topkw, out);

    (void)in_sizes; (void)n_in; (void)out_size; (void)ws_size;
}

// Round 16
// 275.639 us; speedup vs baseline: 1.0555x; 1.0555x over previous
//
#include <hip/hip_runtime.h>
#include <hip/hip_bf16.h>
#include <stdint.h>

typedef float f32x4 __attribute__((ext_vector_type(4)));
typedef short s16x8 __attribute__((ext_vector_type(8)));
typedef short s16x4 __attribute__((ext_vector_type(4)));

__device__ __forceinline__ short f2bf(float x) {
    union { float f; uint32_t u; } v; v.f = x;
    uint32_t r = v.u + 0x7fffu + ((v.u >> 16) & 1u);
    return (short)(r >> 16);
}
__device__ __forceinline__ float bf2f(short b) {
    union { uint32_t u; float f; } v; v.u = ((uint32_t)(uint16_t)b) << 16;
    return v.f;
}
__device__ __forceinline__ void gld16(const void* g, void* l) {
    __builtin_amdgcn_global_load_lds((const __attribute__((address_space(1))) uint32_t*)g,
                                     (__attribute__((address_space(3))) uint32_t*)l, 16, 0, 0);
}

// ---- cvt: q|k|v -> wqkv, sg|su -> wsgsu, o -> wo, sd -> wsd (bf16) ----
__global__ __launch_bounds__(256) void cvt_small_kernel(const float* __restrict__ q, const float* __restrict__ k,
                                                        const float* __restrict__ v, const float* __restrict__ sg,
                                                        const float* __restrict__ su, const float* __restrict__ o,
                                                        const float* __restrict__ sd, short* __restrict__ wqkv,
                                                        short* __restrict__ wsgsu, short* __restrict__ wo,
                                                        short* __restrict__ wsd) {
    size_t i = (size_t)blockIdx.x * 256 + threadIdx.x;  // f32x8 chunk; grid covers exactly 720896
    const float* src; short* dst;
    if (i < 131072) { src = q + i * 8; dst = wqkv + i * 8; }
    else if (i < 163840) { src = k + (i - 131072) * 8; dst = wqkv + 1048576 + (i - 131072) * 8; }
    else if (i < 196608) { src = v + (i - 163840) * 8; dst = wqkv + 1310720 + (i - 163840) * 8; }
    else if (i < 327680) { src = sg + (i - 196608) * 8; dst = wsgsu + (i - 196608) * 8; }
    else if (i < 458752) { src = su + (i - 327680) * 8; dst = wsgsu + 1048576 + (i - 327680) * 8; }
    else if (i < 589824) { src = o + (i - 458752) * 8; dst = wo + (i - 458752) * 8; }
    else { src = sd + (i - 589824) * 8; dst = wsd + (i - 589824) * 8; }
    f32x4 a = ((const f32x4*)src)[0];
    f32x4 b = ((const f32x4*)src)[1];
    s16x8 o8;
    o8[0] = f2bf(a[0]); o8[1] = f2bf(a[1]); o8[2] = f2bf(a[2]); o8[3] = f2bf(a[3]);
    o8[4] = f2bf(b[0]); o8[5] = f2bf(b[1]); o8[6] = f2bf(b[2]); o8[7] = f2bf(b[3]);
    *(s16x8*)dst = o8;
}

// ---------------- RMSNorm (row=1024), writes bf16 ----------------
__global__ __launch_bounds__(256) void rmsnorm_kernel(const float* __restrict__ x, const float* __restrict__ w,
                                                      short* __restrict__ out) {
    int t = blockIdx.x;
    f32x4 v = ((const f32x4*)(x + (size_t)t * 1024))[threadIdx.x];
    float ssq = v[0]*v[0] + v[1]*v[1] + v[2]*v[2] + v[3]*v[3];
#pragma unroll
    for (int o = 1; o < 64; o <<= 1) ssq += __shfl_xor(ssq, o);
    __shared__ float red[4];
    if ((threadIdx.x & 63) == 0) red[threadIdx.x >> 6] = ssq;
    __syncthreads();
    float tot = red[0] + red[1] + red[2] + red[3];
    float rs = rsqrtf(tot * (1.0f / 1024.0f) + 1e-6f);
    f32x4 wv = ((const f32x4*)w)[threadIdx.x];
    s16x4 o4;
#pragma unroll
    for (int j = 0; j < 4; ++j) o4[j] = f2bf(v[j] * rs * wv[j]);
    ((s16x4*)(out + (size_t)t * 1024))[threadIdx.x] = o4;
}

// ---- residual add + RMSNorm; b = 4 bf16 split-K slices; writes res f32, xf bf16, xf32 f32 ----
__global__ __launch_bounds__(256) void addnorm_kernel(const float* __restrict__ a, const short* __restrict__ b,
                                                      const float* __restrict__ w, float* __restrict__ res,
                                                      short* __restrict__ xf, float* __restrict__ xf32) {
    int t = blockIdx.x;
    f32x4 va = ((const f32x4*)(a + (size_t)t * 1024))[threadIdx.x];
    f32x4 vb = {0.f, 0.f, 0.f, 0.f};
#pragma unroll
    for (int z = 0; z < 4; ++z) {
        s16x4 dz = *(const s16x4*)(b + (size_t)z * 2048 * 1024 + (size_t)t * 1024 + threadIdx.x * 4);
#pragma unroll
        for (int j = 0; j < 4; ++j) vb[j] += bf2f(dz[j]);
    }
    f32x4 s = va + vb;
    ((f32x4*)(res + (size_t)t * 1024))[threadIdx.x] = s;
    float ssq = s[0]*s[0] + s[1]*s[1] + s[2]*s[2] + s[3]*s[3];
#pragma unroll
    for (int o = 1; o < 64; o <<= 1) ssq += __shfl_xor(ssq, o);
    __shared__ float red[4];
    if ((threadIdx.x & 63) == 0) red[threadIdx.x >> 6] = ssq;
    __syncthreads();
    float tot = red[0] + red[1] + red[2] + red[3];
    float rs = rsqrtf(tot * (1.0f / 1024.0f) + 1e-6f);
    f32x4 wv = ((const f32x4*)w)[threadIdx.x];
    f32x4 xo;
    s16x4 o4;
#pragma unroll
    for (int j = 0; j < 4; ++j) { xo[j] = s[j] * rs * wv[j]; o4[j] = f2bf(xo[j]); }
    ((f32x4*)(xf32 + (size_t)t * 1024))[threadIdx.x] = xo;
    ((s16x4*)(xf + (size_t)t * 1024))[threadIdx.x] = o4;
}

// ================= GEMM v3 (bf16 B): 128x128, BK=32, global_load_lds both operands =========
__global__ __launch_bounds__(256, 4) void gemm2_kernel(const short* __restrict__ A, const short* __restrict__ Bg,
                                                       void* __restrict__ Cv, int M, int N, int Ktot, int Ksub,
                                                       long long cstride, int store_bf16) {
    __shared__ short As[2][128 * 32];
    __shared__ short Bs[2][128 * 32];
    int bm = blockIdx.x * 128, bn = blockIdx.y * 128;
    int k0 = blockIdx.z * Ksub;
    size_t coff = (size_t)blockIdx.z * cstride;
    int Mloc = M;
    const short* Bt = Bg;
    int tid = threadIdx.x, w = tid >> 6, l = tid & 63;
    int lr = l & 15, lg = l >> 4;
    int rsub = l >> 2, u = l & 3;
    int fs = (rsub & 3) ^ ((rsub >> 2) & 3);
    int colsel = (u ^ fs) * 8;
    int ra = w * 32 + rsub;
    const short* Ap0 = A + (size_t)(bm + ra) * Ktot + k0 + colsel;
    const short* Ap1 = A + (size_t)(bm + ra + 16) * Ktot + k0 + colsel;
    const short* Bp0 = Bt + (size_t)(bn + ra) * Ktot + k0 + colsel;
    const short* Bp1 = Bt + (size_t)(bn + ra + 16) * Ktot + k0 + colsel;
    int lb0 = w * 1024, lb1 = w * 1024 + 512;

    int wm = (w >> 1) * 64, wn = (w & 1) * 64;
    int su = lg ^ (lr & 3) ^ ((lr >> 2) & 3);
    int aoff[4], boff[4];
#pragma unroll
    for (int mf = 0; mf < 4; ++mf) aoff[mf] = (wm + mf * 16 + lr) * 32 + su * 8;
#pragma unroll
    for (int nf = 0; nf < 4; ++nf) boff[nf] = (wn + nf * 16 + lr) * 32 + su * 8;

    f32x4 zero4 = {0.f, 0.f, 0.f, 0.f};
    f32x4 acc[4][4];
#pragma unroll
    for (int mf = 0; mf < 4; ++mf)
#pragma unroll
        for (int nf = 0; nf < 4; ++nf) acc[mf][nf] = zero4;

#define STAGE(buf, kt) do { \
        gld16(Ap0 + (kt) * 32, &As[buf][lb0]); \
        gld16(Ap1 + (kt) * 32, &As[buf][lb1]); \
        gld16(Bp0 + (kt) * 32, &Bs[buf][lb0]); \
        gld16(Bp1 + (kt) * 32, &Bs[buf][lb1]); \
    } while (0)

    int nk = Ksub >> 5;
    STAGE(0, 0);
    asm volatile("s_waitcnt vmcnt(0)");
    __syncthreads();
    for (int kt = 0; kt < nk; ++kt) {
        int cur = kt & 1;
        if (kt + 1 < nk) STAGE(cur ^ 1, kt + 1);
        s16x8 af[4], bfr[4];
#pragma unroll
        for (int mf = 0; mf < 4; ++mf) af[mf] = *(const s16x8*)&As[cur][aoff[mf]];
#pragma unroll
        for (int nf = 0; nf < 4; ++nf) bfr[nf] = *(const s16x8*)&Bs[cur][boff[nf]];
#pragma unroll
        for (int mf = 0; mf < 4; ++mf)
#pragma unroll
            for (int nf = 0; nf < 4; ++nf)
                acc[mf][nf] = __builtin_amdgcn_mfma_f32_16x16x32_bf16(af[mf], bfr[nf], acc[mf][nf], 0, 0, 0);
        __syncthreads();
    }
#undef STAGE
    float* Cf = (float*)Cv;
    short* Cs = (short*)Cv;
#pragma unroll
    for (int mf = 0; mf < 4; ++mf) {
        int rbase = bm + wm + mf * 16 + lg * 4;
#pragma unroll
        for (int r = 0; r < 4; ++r) {
            int grow = rbase + r;
            if (grow < Mloc) {
                size_t cb = coff + (size_t)grow * N + bn + wn + lr;
                if (store_bf16) {
#pragma unroll
                    for (int nf = 0; nf < 4; ++nf) Cs[cb + nf * 16] = f2bf(acc[mf][nf][r]);
                } else {
#pragma unroll
                    for (int nf = 0; nf < 4; ++nf) Cf[cb + nf * 16] = acc[mf][nf][r];
                }
            }
        }
    }
}

// ====== GEMM v4 (f32 B): deep B prefetch (2 reg sets) + raw barrier w/ counted vmcnt ======
// moe (plan!=null): grid(x=N/128, y=planmax, z=ksplit); plan entry = e | m<<5; rows via lists.
#define WAITBAR4 do { __builtin_amdgcn_sched_barrier(0); \
        asm volatile("s_waitcnt vmcnt(4) lgkmcnt(0)" ::: "memory"); \
        __builtin_amdgcn_s_barrier(); __builtin_amdgcn_sched_barrier(0); } while (0)
#define WAITBAR0 do { __builtin_amdgcn_sched_barrier(0); \
        asm volatile("s_waitcnt vmcnt(0) lgkmcnt(0)" ::: "memory"); \
        __builtin_amdgcn_s_barrier(); __builtin_amdgcn_sched_barrier(0); } while (0)

__global__ __launch_bounds__(256, 4) void gemm3_kernel(const short* __restrict__ A, const float* __restrict__ Bg,
                                                       void* __restrict__ Cv, int M, int N, int Ktot, int Ksub,
                                                       long long cstride,
                                                       const int* __restrict__ counts, const int* __restrict__ lists,
                                                       const int* __restrict__ plan, int a_shift, int store_bf16) {
    __shared__ short As[2][128 * 32];
    __shared__ short Bs[2][128 * 32];
    int e, bm, bn, k0, Mloc;
    size_t coff = (size_t)blockIdx.z * cstride;
    const int* rl = nullptr;
    if (plan) {
        int wi = blockIdx.y;
        if (wi >= plan[0]) return;
        int it = plan[1 + wi];
        e = it & 31; bm = (it >> 5) * 128;
        bn = blockIdx.x * 128;
        Mloc = counts[e]; rl = lists + e * 2048;
    } else {
        e = 0; bm = blockIdx.x * 128; bn = blockIdx.y * 128;
        Mloc = M;
    }
    k0 = blockIdx.z * Ksub;
    if (bm >= Mloc) return;
    const float* Bt = Bg + (size_t)e * N * Ktot;
    int tid = threadIdx.x, w = tid >> 6, l = tid & 63;
    int lr = l & 15, lg = l >> 4;
    int rsub = l >> 2, uu = l & 3;
    int fs = (rsub & 3) ^ ((rsub >> 2) & 3);
    int colsel = (uu ^ fs) * 8;
    int ra = w * 32 + rsub;
    int ga0 = bm + ra;       if (ga0 > Mloc - 1) ga0 = Mloc - 1;
    int ga1 = bm + ra + 16;  if (ga1 > Mloc - 1) ga1 = Mloc - 1;
    int ar0 = rl ? (rl[ga0] >> a_shift) : ga0;
    int ar1 = rl ? (rl[ga1] >> a_shift) : ga1;
    const short* Ap0 = A + (size_t)ar0 * Ktot + k0 + colsel;
    const short* Ap1 = A + (size_t)ar1 * Ktot + k0 + colsel;
    const float* Bp0 = Bt + (size_t)(bn + ra) * Ktot + k0 + uu * 8;
    const float* Bp1 = Bt + (size_t)(bn + ra + 16) * Ktot + k0 + uu * 8;
    int lb0 = w * 1024, lb1 = w * 1024 + 512;
    int sb0 = w * 1024 + rsub * 32 + colsel, sb1 = sb0 + 512;

    int wm = (w >> 1) * 64, wn = (w & 1) * 64;
    int su = lg ^ (lr & 3) ^ ((lr >> 2) & 3);
    int aoff[4], boff[4];
#pragma unroll
    for (int mf = 0; mf < 4; ++mf) aoff[mf] = (wm + mf * 16 + lr) * 32 + su * 8;
#pragma unroll
    for (int nf = 0; nf < 4; ++nf) boff[nf] = (wn + nf * 16 + lr) * 32 + su * 8;

    f32x4 zero4 = {0.f, 0.f, 0.f, 0.f};
    f32x4 acc[4][4];
#pragma unroll
    for (int mf = 0; mf < 4; ++mf)
#pragma unroll
        for (int nf = 0; nf < 4; ++nf) acc[mf][nf] = zero4;

    f32x4 bA00, bA01, bA10, bA11, bB00, bB01, bB10, bB11;
#define BLOAD(S, kt) do { \
        const float* p0 = Bp0 + (kt) * 32; const float* p1 = Bp1 + (kt) * 32; \
        S##00 = *(const f32x4*)p0; S##01 = *(const f32x4*)(p0 + 4); \
        S##10 = *(const f32x4*)p1; S##11 = *(const f32x4*)(p1 + 4); \
    } while (0)
#define BWRITE(S, buf) do { \
        s16x8 t0, t1; \
        t0[0] = f2bf(S##00[0]); t0[1] = f2bf(S##00[1]); t0[2] = f2bf(S##00[2]); t0[3] = f2bf(S##00[3]); \
        t0[4] = f2bf(S##01[0]); t0[5] = f2bf(S##01[1]); t0[6] = f2bf(S##01[2]); t0[7] = f2bf(S##01[3]); \
        t1[0] = f2bf(S##10[0]); t1[1] = f2bf(S##10[1]); t1[2] = f2bf(S##10[2]); t1[3] = f2bf(S##10[3]); \
        t1[4] = f2bf(S##11[0]); t1[5] = f2bf(S##11[1]); t1[6] = f2bf(S##11[2]); t1[7] = f2bf(S##11[3]); \
        *(s16x8*)&Bs[buf][sb0] = t0; *(s16x8*)&Bs[buf][sb1] = t1; \
    } while (0)
#define ASTAGE(buf, kt) do { \
        gld16(Ap0 + (kt) * 32, &As[buf][lb0]); \
        gld16(Ap1 + (kt) * 32, &As[buf][lb1]); \
    } while (0)
#define COMPUTE(buf) do { \
        s16x8 af[4], bfr[4]; \
        for (int mf = 0; mf < 4; ++mf) af[mf] = *(const s16x8*)&As[buf][aoff[mf]]; \
        for (int nf = 0; nf < 4; ++nf) bfr[nf] = *(const s16x8*)&Bs[buf][boff[nf]]; \
        for (int mf = 0; mf < 4; ++mf) \
            for (int nf = 0; nf < 4; ++nf) \
                acc[mf][nf] = __builtin_amdgcn_mfma_f32_16x16x32_bf16(af[mf], bfr[nf], acc[mf][nf], 0, 0, 0); \
    } while (0)

    int nk = Ksub >> 5;   // even, >= 2 at all call sites
    BLOAD(bA, 0);
    ASTAGE(0, 0);
    BWRITE(bA, 0);
    BLOAD(bB, 1);
    WAITBAR4;
    for (int kt = 0; kt < nk; kt += 2) {
        {
            if (kt + 1 < nk) ASTAGE(1, kt + 1);
            if (kt + 2 < nk) BLOAD(bA, kt + 2);
            COMPUTE(0);
            if (kt + 1 < nk) BWRITE(bB, 1);
            if (kt + 2 < nk) { WAITBAR4; } else { WAITBAR0; }
        }
        if (kt + 1 >= nk) break;
        {
            if (kt + 2 < nk) ASTAGE(0, kt + 2);
            if (kt + 3 < nk) BLOAD(bB, kt + 3);
            COMPUTE(1);
            if (kt + 2 < nk) BWRITE(bA, 0);
            if (kt + 3 < nk) { WAITBAR4; } else { WAITBAR0; }
        }
    }
#undef BLOAD
#undef BWRITE
#undef ASTAGE
#undef COMPUTE
    float* Cf = (float*)Cv;
    short* Cs = (short*)Cv;
#pragma unroll
    for (int mf = 0; mf < 4; ++mf) {
        int rbase = bm + wm + mf * 16 + lg * 4;
#pragma unroll
        for (int r = 0; r < 4; ++r) {
            int grow = rbase + r;
            if (grow < Mloc) {
                int crow = rl ? rl[grow] : grow;
                size_t cb = coff + (size_t)crow * N + bn + wn + lr;
                if (store_bf16) {
#pragma unroll
                    for (int nf = 0; nf < 4; ++nf) Cs[cb + nf * 16] = f2bf(acc[mf][nf][r]);
                } else {
#pragma unroll
                    for (int nf = 0; nf < 4; ++nf) Cf[cb + nf * 16] = acc[mf][nf][r];
                }
            }
        }
    }
}

// ---- RoPE; input qkv = 4 bf16 split-K slices [4][2048][1536]; out Qr*0.125, Kr, Vt[B,4,64,S] ----
__global__ __launch_bounds__(64) void rope_kernel(const short* __restrict__ qkv, short* __restrict__ Qr,
                                                  short* __restrict__ Kr, short* __restrict__ Vt) {
    int t = blockIdx.x;
    int b = t >> 10, s = t & 1023;
    int l = threadIdx.x;
    __shared__ float cs[32], sn[32], row[1536];
    float acc[24];
#pragma unroll
    for (int c = 0; c < 24; ++c) acc[c] = 0.f;
#pragma unroll
    for (int z = 0; z < 4; ++z) {
        const short* src = qkv + (size_t)z * 2048 * 1536 + (size_t)t * 1536 + l * 24;
#pragma unroll
        for (int c8 = 0; c8 < 3; ++c8) {
            s16x8 v8 = *(const s16x8*)(src + c8 * 8);
#pragma unroll
            for (int j = 0; j < 8; ++j) acc[c8 * 8 + j] += bf2f(v8[j]);
        }
    }
#pragma unroll
    for (int c = 0; c < 24; ++c) row[l * 24 + c] = acc[c];
    if (l < 32) {
        float fr = (float)t * exp2f(-(float)l * 0.41524101186f);
        cs[l] = cosf(fr); sn[l] = sinf(fr);
    }
    __syncthreads();
    int d = l;
    float c = cs[d & 31], sv = sn[d & 31];
#pragma unroll
    for (int h = 0; h < 16; ++h) {
        float x = row[h * 64 + d];
        float rot = (d < 32) ? -row[h * 64 + d + 32] : row[h * 64 + d - 32];
        Qr[((size_t)(b * 16 + h) * 1024 + s) * 64 + d] = f2bf((x * c + rot * sv) * 0.125f);
    }
#pragma unroll
    for (int h = 0; h < 4; ++h) {
        float x = row[1024 + h * 64 + d];
        float rot = (d < 32) ? -row[1024 + h * 64 + d + 32] : row[1024 + h * 64 + d - 32];
        Kr[((size_t)(b * 4 + h) * 1024 + s) * 64 + d] = f2bf(x * c + rot * sv);
        Vt[((size_t)(b * 4 + h) * 64 + d) * 1024 + s] = f2bf(row[1280 + h * 64 + d]);
    }
}

// ---------------- flash attention v2: paired q-tiles + K/V register prefetch ----------------
struct KV { s16x8 k[4]; s16x8 v[4]; };
__device__ __forceinline__ void kv_load(KV& r, const short* Kb, const short* Vb, int k0, int lr, int lg) {
    const short* K0 = Kb + (size_t)(k0 + lr) * 64 + lg * 8;
    const short* K1 = Kb + (size_t)(k0 + 16 + lr) * 64 + lg * 8;
    r.k[0] = *(const s16x8*)K0;
    r.k[1] = *(const s16x8*)(K0 + 32);
    r.k[2] = *(const s16x8*)K1;
    r.k[3] = *(const s16x8*)(K1 + 32);
#pragma unroll
    for (int dt = 0; dt < 4; ++dt)
        r.v[dt] = *(const s16x8*)(Vb + (size_t)(dt * 16 + lr) * 1024 + k0 + lg * 8);
}
__device__ __forceinline__ void chain_step(const KV& kv, s16x8 qf0, s16x8 qf1, f32x4* o,
                                           float& m, float& lsum, short* Pl,
                                           int lr, int lg, int k0, int qmask) {
    f32x4 z = {0.f, 0.f, 0.f, 0.f};
    f32x4 sc0 = z, sc1 = z;
    sc0 = __builtin_amdgcn_mfma_f32_16x16x32_bf16(kv.k[0], qf0, sc0, 0, 0, 0);
    sc0 = __builtin_amdgcn_mfma_f32_16x16x32_bf16(kv.k[1], qf1, sc0, 0, 0, 0);
    sc1 = __builtin_amdgcn_mfma_f32_16x16x32_bf16(kv.k[2], qf0, sc1, 0, 0, 0);
    sc1 = __builtin_amdgcn_mfma_f32_16x16x32_bf16(kv.k[3], qf1, sc1, 0, 0, 0);
#pragma unroll
    for (int r = 0; r < 4; ++r) {
        if (k0 + lg * 4 + r > qmask) sc0[r] = -1e30f;
        if (k0 + 16 + lg * 4 + r > qmask) sc1[r] = -1e30f;
    }
    float tm = fmaxf(fmaxf(fmaxf(sc0[0], sc0[1]), fmaxf(sc0[2], sc0[3])),
                     fmaxf(fmaxf(sc1[0], sc1[1]), fmaxf(sc1[2], sc1[3])));
    tm = fmaxf(tm, __shfl_xor(tm, 16));
    tm = fmaxf(tm, __shfl_xor(tm, 32));
    float newm = fmaxf(m, tm);
    float fac = __expf(m - newm);
    float p[8];
#pragma unroll
    for (int r = 0; r < 4; ++r) { p[r] = __expf(sc0[r] - newm); p[4 + r] = __expf(sc1[r] - newm); }
    float ts = ((p[0] + p[1]) + (p[2] + p[3])) + ((p[4] + p[5]) + (p[6] + p[7]));
    ts += __shfl_xor(ts, 16);
    ts += __shfl_xor(ts, 32);
    lsum = lsum * fac + ts;
    m = newm;
    s16x4 w0, w1;
#pragma unroll
    for (int r = 0; r < 4; ++r) { w0[r] = f2bf(p[r]); w1[r] = f2bf(p[4 + r]); }
    *(s16x4*)&Pl[lr * 40 + lg * 4] = w0;
    *(s16x4*)&Pl[lr * 40 + 16 + lg * 4] = w1;
    s16x8 pf = *(const s16x8*)&Pl[lr * 40 + lg * 8];
#pragma unroll
    for (int dt = 0; dt < 4; ++dt) {
        o[dt] *= fac;
        o[dt] = __builtin_amdgcn_mfma_f32_16x16x32_bf16(kv.v[dt], pf, o[dt], 0, 0, 0);
    }
}

__global__ __launch_bounds__(64) void attn_kernel(const short* __restrict__ Qr, const short* __restrict__ Kr,
                                                  const short* __restrict__ Vt, short* __restrict__ attn_out) {
    int p = blockIdx.x;
    int hb = blockIdx.y;
    int b = hb >> 4, h = hb & 15, kv = h >> 2;
    int l = threadIdx.x;
    int lr = l & 15, lg = l >> 4;
    int q0A = p * 16, q0B = (63 - p) * 16;
    __shared__ short PlA[16 * 40], PlB[16 * 40];
    const short* Qh = Qr + (size_t)(b * 16 + h) * 1024 * 64;
    s16x8 qA0 = *(const s16x8*)(Qh + (size_t)(q0A + lr) * 64 + lg * 8);
    s16x8 qA1 = *(const s16x8*)(Qh + (size_t)(q0A + lr) * 64 + 32 + lg * 8);
    s16x8 qB0 = *(const s16x8*)(Qh + (size_t)(q0B + lr) * 64 + lg * 8);
    s16x8 qB1 = *(const s16x8*)(Qh + (size_t)(q0B + lr) * 64 + 32 + lg * 8);
    const short* Kbase = Kr + (size_t)(b * 4 + kv) * 1024 * 64;
    const short* Vbase = Vt + (size_t)(b * 4 + kv) * 64 * 1024;

    f32x4 zero4 = {0.f, 0.f, 0.f, 0.f};
    f32x4 oA[4], oB[4];
#pragma unroll
    for (int dt = 0; dt < 4; ++dt) { oA[dt] = zero4; oB[dt] = zero4; }
    float mA = -1e30f, lsA = 0.f, mB = -1e30f, lsB = 0.f;
    int ntA = (q0A + 47) >> 5, ntB = (q0B + 47) >> 5;
    int qmA = q0A + lr, qmB = q0B + lr;
    const int BIG = 1 << 29;

    KV b0, b1;
    kv_load(b0, Kbase, Vbase, 0, lr, lg);
    for (int kt = 0; kt < ntB; kt += 2) {
        if (kt + 1 < ntB) kv_load(b1, Kbase, Vbase, (kt + 1) * 32, lr, lg);
        if (kt < ntA) chain_step(b0, qA0, qA1, oA, mA, lsA, PlA, lr, lg, kt * 32,
                                 (kt == ntA - 1) ? qmA : BIG);
        chain_step(b0, qB0, qB1, oB, mB, lsB, PlB, lr, lg, kt * 32,
                   (kt == ntB - 1) ? qmB : BIG);
        if (kt + 1 >= ntB) break;
        if (kt + 2 < ntB) kv_load(b0, Kbase, Vbase, (kt + 2) * 32, lr, lg);
        if (kt + 1 < ntA) chain_step(b1, qA0, qA1, oA, mA, lsA, PlA, lr, lg, (kt + 1) * 32,
                                     (kt + 1 == ntA - 1) ? qmA : BIG);
        chain_step(b1, qB0, qB1, oB, mB, lsB, PlB, lr, lg, (kt + 1) * 32,
                   (kt + 1 == ntB - 1) ? qmB : BIG);
    }
    float invA = 1.f / lsA, invB = 1.f / lsB;
    short* oa = attn_out + ((size_t)(b * 1024 + q0A + lr)) * 1024 + h * 64;
    short* ob = attn_out + ((size_t)(b * 1024 + q0B + lr)) * 1024 + h * 64;
#pragma unroll
    for (int dt = 0; dt < 4; ++dt)
#pragma unroll
        for (int r = 0; r < 4; ++r) {
            oa[dt * 16 + lg * 4 + r] = f2bf(oA[dt][r] * invA);
            ob[dt * 16 + lg * 4 + r] = f2bf(oB[dt][r] * invB);
        }
}

// ---------------- router R1: logits + top-k per token (no atomics) ----------------
__global__ __launch_bounds__(256) void router_topk_kernel(const float* __restrict__ x32, const float* __restrict__ gw,
                                                          const float* __restrict__ eb, float* __restrict__ tw,
                                                          int* __restrict__ tidx) {
    int t = blockIdx.x * 4 + (threadIdx.x >> 6);
    int l = threadIdx.x & 63;
    const float* x = x32 + (size_t)t * 1024;
    f32x4 xv[4];
#pragma unroll
    for (int j = 0; j < 4; ++j) xv[j] = *(const f32x4*)(x + j * 256 + l * 4);
    float acc[16];
#pragma unroll
    for (int e = 0; e < 16; ++e) {
        float a = 0.f;
#pragma unroll
        for (int j = 0; j < 4; ++j) {
            f32x4 g = *(const f32x4*)(gw + (size_t)e * 1024 + j * 256 + l * 4);
            a += xv[j][0]*g[0] + xv[j][1]*g[1] + xv[j][2]*g[2] + xv[j][3]*g[3];
        }
        acc[e] = a;
    }
#pragma unroll
    for (int e = 0; e < 16; ++e) {
#pragma unroll
        for (int o = 1; o < 64; o <<= 1) acc[e] += __shfl_xor(acc[e], o);
    }
    if (l == 0) {
        float score[16], sfc[16];
#pragma unroll
        for (int e = 0; e < 16; ++e) {
            score[e] = 1.f / (1.f + __expf(-acc[e]));
            sfc[e] = score[e] + eb[e];
        }
        float gs[4];
#pragma unroll
        for (int g = 0; g < 4; ++g)
            gs[g] = fmaxf(fmaxf(sfc[4 * g], sfc[4 * g + 1]), fmaxf(sfc[4 * g + 2], sfc[4 * g + 3]));
        int g1 = 0;
        for (int g = 1; g < 4; ++g) if (gs[g] > gs[g1]) g1 = g;
        int g2 = -1;
        for (int g = 0; g < 4; ++g) {
            if (g == g1) continue;
            if (g2 < 0 || gs[g] > gs[g2]) g2 = g;
        }
        float masked[16];
#pragma unroll
        for (int e = 0; e < 16; ++e) {
            int g = e >> 2;
            masked[e] = (g == g1 || g == g2) ? sfc[e] : 0.0f;
        }
        float tot = 1e-20f;
        int idx[4]; float wv[4];
        for (int k = 0; k < 4; ++k) {
            int bi = 0;
            float bv = -1e30f;
            for (int e2 = 0; e2 < 16; ++e2)
                if (masked[e2] > bv) { bv = masked[e2]; bi = e2; }
            idx[k] = bi;
            wv[k] = score[bi];
            masked[bi] = -1e30f;
            tot += wv[k];
        }
        for (int k = 0; k < 4; ++k) {
            tw[t * 4 + k] = wv[k] / tot * 2.5f;
            tidx[t * 4 + k] = idx[k];
        }
    }
}

// ---------------- router R2: per-expert ordered compaction (1 wave per expert) ----------------
__global__ __launch_bounds__(64) void router_lists_kernel(const int* __restrict__ tidx, int* __restrict__ counts,
                                                          int* __restrict__ lists) {
    int e = blockIdx.x;
    int l = threadIdx.x;
    int base = 0;
    for (int it = 0; it < 128; ++it) {
        int p = it * 64 + l;
        bool match = (tidx[p] == e);
        unsigned long long mask = __ballot(match);
        int pos = __popcll(mask & ((1ull << l) - 1ull));
        if (match) lists[e * 2048 + base + pos] = p;
        base += __popcll(mask);
    }
    if (l == 0) counts[e] = base;
}

// ---- build (expert, mblock) work list: plan[0]=count, plan[1+i] = e | (m<<5) ----
__global__ void plan_kernel(const int* __restrict__ counts, int* __restrict__ plan) {
    if (threadIdx.x == 0) {
        int n = 0;
        for (int e = 0; e < 16; ++e) {
            int nb = (counts[e] + 127) >> 7;
            for (int m2 = 0; m2 < nb; ++m2) plan[1 + n++] = e | (m2 << 5);
        }
        plan[0] = n;
    }
}

// ---- silu-mul routed: gu 2 bf16 slices [2][8192][1024] -> hid[p][512] bf16 ----
__global__ __launch_bounds__(128) void silu_routed_kernel(const short* __restrict__ gu, short* __restrict__ hid) {
    int pr = blockIdx.x;
    int j = threadIdx.x * 4;
    float g[4] = {0.f, 0.f, 0.f, 0.f}, u2[4] = {0.f, 0.f, 0.f, 0.f};
#pragma unroll
    for (int z = 0; z < 2; ++z) {
        const short* base = gu + (size_t)z * 8192 * 1024 + (size_t)pr * 1024;
        s16x4 gz = *(const s16x4*)(base + j);
        s16x4 uz = *(const s16x4*)(base + 512 + j);
#pragma unroll
        for (int k = 0; k < 4; ++k) { g[k] += bf2f(gz[k]); u2[k] += bf2f(uz[k]); }
    }
    s16x4 o;
#pragma unroll
    for (int k = 0; k < 4; ++k) o[k] = f2bf(g[k] / (1.f + __expf(-g[k])) * u2[k]);
    *(s16x4*)(hid + (size_t)pr * 512 + j) = o;
}

// ---- silu-mul shared: sgsu 2 bf16 slices [2][2048][2048] -> shhid[t][1024] bf16 ----
__global__ __launch_bounds__(256) void silu_shared_kernel(const short* __restrict__ gu, short* __restrict__ h) {
    int t = blockIdx.x;
    int j = threadIdx.x * 4;
    float g[4] = {0.f, 0.f, 0.f, 0.f}, u2[4] = {0.f, 0.f, 0.f, 0.f};
#pragma unroll
    for (int z = 0; z < 2; ++z) {
        const short* base = gu + (size_t)z * 2048 * 2048 + (size_t)t * 2048;
        s16x4 gz = *(const s16x4*)(base + j);
        s16x4 uz = *(const s16x4*)(base + 1024 + j);
#pragma unroll
        for (int k = 0; k < 4; ++k) { g[k] += bf2f(gz[k]); u2[k] += bf2f(uz[k]); }
    }
    s16x4 o;
#pragma unroll
    for (int k = 0; k < 4; ++k) o[k] = f2bf(g[k] / (1.f + __expf(-g[k])) * u2[k]);
    *(s16x4*)(h + (size_t)t * 1024 + j) = o;
}

// ---- combine: out = res2 + sum_z sd[z] + sum_s w_s * down[t*4+s] ----
__global__ __launch_bounds__(256) void combine_kernel(const float* __restrict__ res2, const short* __restrict__ sdp,
                                                      const short* __restrict__ slots, const float* __restrict__ tw,
                                                      float* __restrict__ out) {
    int t = blockIdx.x;
    int i = threadIdx.x;
    f32x4 acc = ((const f32x4*)(res2 + (size_t)t * 1024))[i];
#pragma unroll
    for (int z = 0; z < 4; ++z) {
        s16x4 d = *(const s16x4*)(sdp + (size_t)z * 2048 * 1024 + (size_t)t * 1024 + i * 4);
#pragma unroll
        for (int j = 0; j < 4; ++j) acc[j] += bf2f(d[j]);
    }
#pragma unroll
    for (int s = 0; s < 4; ++s) {
        float w = tw[t * 4 + s];
        s16x4 d = ((const s16x4*)(slots + (size_t)(t * 4 + s) * 1024))[i];
#pragma unroll
        for (int j = 0; j < 4; ++j) acc[j] += bf2f(d[j]) * w;
    }
    ((f32x4*)(out + (size_t)t * 1024))[i] = acc;
}

extern "C" void kernel_launch(void* const* d_in, const int* in_sizes, int n_in,
                              void* d_out, int out_size, void* d_ws, size_t ws_size,
                              hipStream_t stream) {
    const float* hidden = (const float*)d_in[0];
    const float* ln1 = (const float*)d_in[2];
    const float* ln2 = (const float*)d_in[3];
    const float* qw = (const float*)d_in[4];
    const float* kw = (const float*)d_in[5];
    const float* vw = (const float*)d_in[6];
    const float* ow = (const float*)d_in[7];
    const float* gatew = (const float*)d_in[8];
    const float* ebias = (const float*)d_in[9];
    const float* wgu = (const float*)d_in[10];
    const float* wd = (const float*)d_in[11];
    const float* sgw = (const float*)d_in[12];
    const float* suw = (const float*)d_in[13];
    const float* sdw = (const float*)d_in[14];
    float* out = (float*)d_out;

    char* base = (char*)d_ws;
    size_t off = 0;
    auto alloc = [&](size_t bytes) -> char* {
        char* r = base + off;
        off += (bytes + 255) & ~(size_t)255;
        return r;
    };
    const size_t MB = 1u << 20;

    // ---- persistent weights (bf16: qkv, sgsu, o, sd)
    short* wqkv_b = (short*)alloc((size_t)1536 * 1024 * 2);
    short* wsgsu_b= (short*)alloc((size_t)2048 * 1024 * 2);
    short* wo_b   = (short*)alloc((size_t)1024 * 1024 * 2);
    short* wsd_b  = (short*)alloc((size_t)1024 * 1024 * 2);
    // ---- persistent activations / routing
    float* res2 = (float*)alloc((size_t)2048 * 1024 * 4);
    short* xf   = (short*)alloc((size_t)2048 * 1024 * 2);
    float* topkw = (float*)alloc(2048 * 4 * 4);
    int* tidx   = (int*)alloc(8192 * 4);
    int* counts = (int*)alloc(64);
    int* lists  = (int*)alloc(16 * 2048 * 4);
    int* plan   = (int*)alloc(512);
    short* shhid = (short*)alloc((size_t)2048 * 1024 * 2);
    short* hid   = (short*)alloc((size_t)8192 * 512 * 2);

    // ---- overlay region (50 MiB), sequential phases
    char* ov = alloc(50 * MB);
    short* xn1       = (short*)(ov);                 // 4 MB
    short* qkv_part  = (short*)(ov + 4 * MB);        // 4 slices x 6 MB = 24 MB
    short* Qr        = (short*)(ov);                 // 4 MB (xn1 dead)
    short* Kr        = (short*)(ov + 28 * MB);       // 1 MB
    short* Vt        = (short*)(ov + 29 * MB);       // 1 MB
    short* attn_out  = (short*)(ov + 30 * MB);       // 4 MB
    short* attnproj_part = (short*)(ov + 34 * MB);   // 4 slices x 4 MB = 16 MB
    float* xf32      = (float*)(ov);                 // 8 MB (Qr dead after attn)
    short* upbuf     = (short*)(ov);                 // 32 MB: sgsu 2x8MB, then gu 2x16MB
    short* down_slot = (short*)(ov);                 // 16 MB (upbuf dead after silu_routed)
    short* sd_part   = (short*)(ov + 16 * MB);       // 4 slices x 4 MB = 16 MB

    // ---- weight conversion (qkv + sgsu + o + sd)
    cvt_small_kernel<<<2816, 256, 0, stream>>>(qw, kw, vw, sgw, suw, ow, sdw,
                                               wqkv_b, wsgsu_b, wo_b, wsd_b);

    // ---- attention block
    rmsnorm_kernel<<<2048, 256, 0, stream>>>(hidden, ln1, xn1);
    gemm2_kernel<<<dim3(16, 12, 4), 256, 0, stream>>>(xn1, wqkv_b, qkv_part, 2048, 1536, 1024, 256,
                                                      2048LL * 1536, 1);
    rope_kernel<<<2048, 64, 0, stream>>>(qkv_part, Qr, Kr, Vt);
    attn_kernel<<<dim3(32, 32, 1), 64, 0, stream>>>(Qr, Kr, Vt, attn_out);
    gemm2_kernel<<<dim3(16, 8, 4), 256, 0, stream>>>(attn_out, wo_b, attnproj_part, 2048, 1024, 1024, 256,
                                                     2048LL * 1024, 1);
    addnorm_kernel<<<2048, 256, 0, stream>>>(hidden, attnproj_part, ln2, res2, xf, xf32);

    // ---- router (atomic-free) + plan
    router_topk_kernel<<<512, 256, 0, stream>>>(xf32, gatew, ebias, topkw, tidx);
    router_lists_kernel<<<16, 64, 0, stream>>>(tidx, counts, lists);
    plan_kernel<<<1, 64, 0, stream>>>(counts, plan);

    // ---- shared expert up (sg|su fused bf16 B, split-K 2) + silu
    gemm2_kernel<<<dim3(16, 16, 2), 256, 0, stream>>>(xf, wsgsu_b, upbuf, 2048, 2048, 1024, 512,
                                                      2048LL * 2048, 1);
    silu_shared_kernel<<<2048, 256, 0, stream>>>(upbuf, shhid);

    // ---- routed experts up (f32 B direct, plan-mode, split-K 2) + silu
    gemm3_kernel<<<dim3(8, 80, 2), 256, 0, stream>>>(xf, wgu, upbuf, 0, 1024, 1024, 512,
                                                     8192LL * 1024, counts, lists, plan, 2, 1);
    silu_routed_kernel<<<8192, 128, 0, stream>>>(upbuf, hid);

    // ---- down projections
    gemm3_kernel<<<dim3(8, 80, 1), 256, 0, stream>>>(hid, wd, down_slot, 0, 1024, 512, 512,
                                                     0LL, counts, lists, plan, 0, 1);
    gemm2_kernel<<<dim3(16, 8, 4), 256, 0, stream>>>(shhid, wsd_b, sd_part, 2048, 1024, 1024, 256,
                                                     2048LL * 1024, 1);

    // ---- combine
    combine_kernel<<<2048, 256, 0, stream>>>(res2, sd_part, down_slot, topkw, out);

    (void)in_sizes; (void)n_in; (void)out_size; (void)ws_size;
}

// Round 17
// 267.565 us; speedup vs baseline: 1.0873x; 1.0302x over previous
//
#include <hip/hip_runtime.h>
#include <hip/hip_bf16.h>
#include <stdint.h>

typedef float f32x4 __attribute__((ext_vector_type(4)));
typedef short s16x8 __attribute__((ext_vector_type(8)));
typedef short s16x4 __attribute__((ext_vector_type(4)));

__device__ __forceinline__ short f2bf(float x) {
    union { float f; uint32_t u; } v; v.f = x;
    uint32_t r = v.u + 0x7fffu + ((v.u >> 16) & 1u);
    return (short)(r >> 16);
}
__device__ __forceinline__ float bf2f(short b) {
    union { uint32_t u; float f; } v; v.u = ((uint32_t)(uint16_t)b) << 16;
    return v.f;
}
__device__ __forceinline__ void gld16(const void* g, void* l) {
    __builtin_amdgcn_global_load_lds((const __attribute__((address_space(1))) uint32_t*)g,
                                     (__attribute__((address_space(3))) uint32_t*)l, 16, 0, 0);
}

// ---- cvt: q|k|v -> wqkv, sg|su -> wsgsu, o -> wo, sd -> wsd (bf16) ----
__global__ __launch_bounds__(256) void cvt_small_kernel(const float* __restrict__ q, const float* __restrict__ k,
                                                        const float* __restrict__ v, const float* __restrict__ sg,
                                                        const float* __restrict__ su, const float* __restrict__ o,
                                                        const float* __restrict__ sd, short* __restrict__ wqkv,
                                                        short* __restrict__ wsgsu, short* __restrict__ wo,
                                                        short* __restrict__ wsd) {
    size_t i = (size_t)blockIdx.x * 256 + threadIdx.x;  // f32x8 chunk; grid covers exactly 720896
    const float* src; short* dst;
    if (i < 131072) { src = q + i * 8; dst = wqkv + i * 8; }
    else if (i < 163840) { src = k + (i - 131072) * 8; dst = wqkv + 1048576 + (i - 131072) * 8; }
    else if (i < 196608) { src = v + (i - 163840) * 8; dst = wqkv + 1310720 + (i - 163840) * 8; }
    else if (i < 327680) { src = sg + (i - 196608) * 8; dst = wsgsu + (i - 196608) * 8; }
    else if (i < 458752) { src = su + (i - 327680) * 8; dst = wsgsu + 1048576 + (i - 327680) * 8; }
    else if (i < 589824) { src = o + (i - 458752) * 8; dst = wo + (i - 458752) * 8; }
    else { src = sd + (i - 589824) * 8; dst = wsd + (i - 589824) * 8; }
    f32x4 a = ((const f32x4*)src)[0];
    f32x4 b = ((const f32x4*)src)[1];
    s16x8 o8;
    o8[0] = f2bf(a[0]); o8[1] = f2bf(a[1]); o8[2] = f2bf(a[2]); o8[3] = f2bf(a[3]);
    o8[4] = f2bf(b[0]); o8[5] = f2bf(b[1]); o8[6] = f2bf(b[2]); o8[7] = f2bf(b[3]);
    *(s16x8*)dst = o8;
}

// ---------------- RMSNorm (row=1024), writes bf16 ----------------
__global__ __launch_bounds__(256) void rmsnorm_kernel(const float* __restrict__ x, const float* __restrict__ w,
                                                      short* __restrict__ out) {
    int t = blockIdx.x;
    f32x4 v = ((const f32x4*)(x + (size_t)t * 1024))[threadIdx.x];
    float ssq = v[0]*v[0] + v[1]*v[1] + v[2]*v[2] + v[3]*v[3];
#pragma unroll
    for (int o = 1; o < 64; o <<= 1) ssq += __shfl_xor(ssq, o);
    __shared__ float red[4];
    if ((threadIdx.x & 63) == 0) red[threadIdx.x >> 6] = ssq;
    __syncthreads();
    float tot = red[0] + red[1] + red[2] + red[3];
    float rs = rsqrtf(tot * (1.0f / 1024.0f) + 1e-6f);
    f32x4 wv = ((const f32x4*)w)[threadIdx.x];
    s16x4 o4;
#pragma unroll
    for (int j = 0; j < 4; ++j) o4[j] = f2bf(v[j] * rs * wv[j]);
    ((s16x4*)(out + (size_t)t * 1024))[threadIdx.x] = o4;
}

// ---- residual add + RMSNorm; b = 4 bf16 split-K slices; writes res f32, xf bf16, xf32 f32 ----
__global__ __launch_bounds__(256) void addnorm_kernel(const float* __restrict__ a, const short* __restrict__ b,
                                                      const float* __restrict__ w, float* __restrict__ res,
                                                      short* __restrict__ xf, float* __restrict__ xf32) {
    int t = blockIdx.x;
    f32x4 va = ((const f32x4*)(a + (size_t)t * 1024))[threadIdx.x];
    f32x4 vb = {0.f, 0.f, 0.f, 0.f};
#pragma unroll
    for (int z = 0; z < 4; ++z) {
        s16x4 dz = *(const s16x4*)(b + (size_t)z * 2048 * 1024 + (size_t)t * 1024 + threadIdx.x * 4);
#pragma unroll
        for (int j = 0; j < 4; ++j) vb[j] += bf2f(dz[j]);
    }
    f32x4 s = va + vb;
    ((f32x4*)(res + (size_t)t * 1024))[threadIdx.x] = s;
    float ssq = s[0]*s[0] + s[1]*s[1] + s[2]*s[2] + s[3]*s[3];
#pragma unroll
    for (int o = 1; o < 64; o <<= 1) ssq += __shfl_xor(ssq, o);
    __shared__ float red[4];
    if ((threadIdx.x & 63) == 0) red[threadIdx.x >> 6] = ssq;
    __syncthreads();
    float tot = red[0] + red[1] + red[2] + red[3];
    float rs = rsqrtf(tot * (1.0f / 1024.0f) + 1e-6f);
    f32x4 wv = ((const f32x4*)w)[threadIdx.x];
    f32x4 xo;
    s16x4 o4;
#pragma unroll
    for (int j = 0; j < 4; ++j) { xo[j] = s[j] * rs * wv[j]; o4[j] = f2bf(xo[j]); }
    ((f32x4*)(xf32 + (size_t)t * 1024))[threadIdx.x] = xo;
    ((s16x4*)(xf + (size_t)t * 1024))[threadIdx.x] = o4;
}

// ================= GEMM v3 (bf16 B): 128x128, BK=32, global_load_lds both operands =========
__global__ __launch_bounds__(256, 4) void gemm2_kernel(const short* __restrict__ A, const short* __restrict__ Bg,
                                                       void* __restrict__ Cv, int M, int N, int Ktot, int Ksub,
                                                       long long cstride, int store_bf16) {
    __shared__ short As[2][128 * 32];
    __shared__ short Bs[2][128 * 32];
    int bm = blockIdx.x * 128, bn = blockIdx.y * 128;
    int k0 = blockIdx.z * Ksub;
    size_t coff = (size_t)blockIdx.z * cstride;
    int Mloc = M;
    const short* Bt = Bg;
    int tid = threadIdx.x, w = tid >> 6, l = tid & 63;
    int lr = l & 15, lg = l >> 4;
    int rsub = l >> 2, u = l & 3;
    int fs = (rsub & 3) ^ ((rsub >> 2) & 3);
    int colsel = (u ^ fs) * 8;
    int ra = w * 32 + rsub;
    const short* Ap0 = A + (size_t)(bm + ra) * Ktot + k0 + colsel;
    const short* Ap1 = A + (size_t)(bm + ra + 16) * Ktot + k0 + colsel;
    const short* Bp0 = Bt + (size_t)(bn + ra) * Ktot + k0 + colsel;
    const short* Bp1 = Bt + (size_t)(bn + ra + 16) * Ktot + k0 + colsel;
    int lb0 = w * 1024, lb1 = w * 1024 + 512;

    int wm = (w >> 1) * 64, wn = (w & 1) * 64;
    int su = lg ^ (lr & 3) ^ ((lr >> 2) & 3);
    int aoff[4], boff[4];
#pragma unroll
    for (int mf = 0; mf < 4; ++mf) aoff[mf] = (wm + mf * 16 + lr) * 32 + su * 8;
#pragma unroll
    for (int nf = 0; nf < 4; ++nf) boff[nf] = (wn + nf * 16 + lr) * 32 + su * 8;

    f32x4 zero4 = {0.f, 0.f, 0.f, 0.f};
    f32x4 acc[4][4];
#pragma unroll
    for (int mf = 0; mf < 4; ++mf)
#pragma unroll
        for (int nf = 0; nf < 4; ++nf) acc[mf][nf] = zero4;

#define STAGE(buf, kt) do { \
        gld16(Ap0 + (kt) * 32, &As[buf][lb0]); \
        gld16(Ap1 + (kt) * 32, &As[buf][lb1]); \
        gld16(Bp0 + (kt) * 32, &Bs[buf][lb0]); \
        gld16(Bp1 + (kt) * 32, &Bs[buf][lb1]); \
    } while (0)

    int nk = Ksub >> 5;
    STAGE(0, 0);
    asm volatile("s_waitcnt vmcnt(0)");
    __syncthreads();
    for (int kt = 0; kt < nk; ++kt) {
        int cur = kt & 1;
        if (kt + 1 < nk) STAGE(cur ^ 1, kt + 1);
        s16x8 af[4], bfr[4];
#pragma unroll
        for (int mf = 0; mf < 4; ++mf) af[mf] = *(const s16x8*)&As[cur][aoff[mf]];
#pragma unroll
        for (int nf = 0; nf < 4; ++nf) bfr[nf] = *(const s16x8*)&Bs[cur][boff[nf]];
#pragma unroll
        for (int mf = 0; mf < 4; ++mf)
#pragma unroll
            for (int nf = 0; nf < 4; ++nf)
                acc[mf][nf] = __builtin_amdgcn_mfma_f32_16x16x32_bf16(af[mf], bfr[nf], acc[mf][nf], 0, 0, 0);
        __syncthreads();
    }
#undef STAGE
    float* Cf = (float*)Cv;
    short* Cs = (short*)Cv;
#pragma unroll
    for (int mf = 0; mf < 4; ++mf) {
        int rbase = bm + wm + mf * 16 + lg * 4;
#pragma unroll
        for (int r = 0; r < 4; ++r) {
            int grow = rbase + r;
            if (grow < Mloc) {
                size_t cb = coff + (size_t)grow * N + bn + wn + lr;
                if (store_bf16) {
#pragma unroll
                    for (int nf = 0; nf < 4; ++nf) Cs[cb + nf * 16] = f2bf(acc[mf][nf][r]);
                } else {
#pragma unroll
                    for (int nf = 0; nf < 4; ++nf) Cf[cb + nf * 16] = acc[mf][nf][r];
                }
            }
        }
    }
}

// ====== GEMM v4 (f32 B): deep B prefetch (2 reg sets) + raw barrier w/ counted vmcnt ======
// moe (plan!=null): grid(x=N/128, y=planmax, z=ksplit); plan entry = e | m<<5; rows via lists.
#define WAITBAR4 do { __builtin_amdgcn_sched_barrier(0); \
        asm volatile("s_waitcnt vmcnt(4) lgkmcnt(0)" ::: "memory"); \
        __builtin_amdgcn_s_barrier(); __builtin_amdgcn_sched_barrier(0); } while (0)
#define WAITBAR0 do { __builtin_amdgcn_sched_barrier(0); \
        asm volatile("s_waitcnt vmcnt(0) lgkmcnt(0)" ::: "memory"); \
        __builtin_amdgcn_s_barrier(); __builtin_amdgcn_sched_barrier(0); } while (0)

__global__ __launch_bounds__(256, 4) void gemm3_kernel(const short* __restrict__ A, const float* __restrict__ Bg,
                                                       void* __restrict__ Cv, int M, int N, int Ktot, int Ksub,
                                                       long long cstride,
                                                       const int* __restrict__ counts, const int* __restrict__ lists,
                                                       const int* __restrict__ plan, int a_shift, int store_bf16) {
    __shared__ short As[2][128 * 32];
    __shared__ short Bs[2][128 * 32];
    int e, bm, bn, k0, Mloc;
    size_t coff = (size_t)blockIdx.z * cstride;
    const int* rl = nullptr;
    if (plan) {
        int wi = blockIdx.y;
        if (wi >= plan[0]) return;
        int it = plan[1 + wi];
        e = it & 31; bm = (it >> 5) * 128;
        bn = blockIdx.x * 128;
        Mloc = counts[e]; rl = lists + e * 2048;
    } else {
        e = 0; bm = blockIdx.x * 128; bn = blockIdx.y * 128;
        Mloc = M;
    }
    k0 = blockIdx.z * Ksub;
    if (bm >= Mloc) return;
    const float* Bt = Bg + (size_t)e * N * Ktot;
    int tid = threadIdx.x, w = tid >> 6, l = tid & 63;
    int lr = l & 15, lg = l >> 4;
    int rsub = l >> 2, uu = l & 3;
    int fs = (rsub & 3) ^ ((rsub >> 2) & 3);
    int colsel = (uu ^ fs) * 8;
    int ra = w * 32 + rsub;
    int ga0 = bm + ra;       if (ga0 > Mloc - 1) ga0 = Mloc - 1;
    int ga1 = bm + ra + 16;  if (ga1 > Mloc - 1) ga1 = Mloc - 1;
    int ar0 = rl ? (rl[ga0] >> a_shift) : ga0;
    int ar1 = rl ? (rl[ga1] >> a_shift) : ga1;
    const short* Ap0 = A + (size_t)ar0 * Ktot + k0 + colsel;
    const short* Ap1 = A + (size_t)ar1 * Ktot + k0 + colsel;
    const float* Bp0 = Bt + (size_t)(bn + ra) * Ktot + k0 + uu * 8;
    const float* Bp1 = Bt + (size_t)(bn + ra + 16) * Ktot + k0 + uu * 8;
    int lb0 = w * 1024, lb1 = w * 1024 + 512;
    int sb0 = w * 1024 + rsub * 32 + colsel, sb1 = sb0 + 512;

    int wm = (w >> 1) * 64, wn = (w & 1) * 64;
    int su = lg ^ (lr & 3) ^ ((lr >> 2) & 3);
    int aoff[4], boff[4];
#pragma unroll
    for (int mf = 0; mf < 4; ++mf) aoff[mf] = (wm + mf * 16 + lr) * 32 + su * 8;
#pragma unroll
    for (int nf = 0; nf < 4; ++nf) boff[nf] = (wn + nf * 16 + lr) * 32 + su * 8;

    f32x4 zero4 = {0.f, 0.f, 0.f, 0.f};
    f32x4 acc[4][4];
#pragma unroll
    for (int mf = 0; mf < 4; ++mf)
#pragma unroll
        for (int nf = 0; nf < 4; ++nf) acc[mf][nf] = zero4;

    f32x4 bA00, bA01, bA10, bA11, bB00, bB01, bB10, bB11;
#define BLOAD(S, kt) do { \
        const float* p0 = Bp0 + (kt) * 32; const float* p1 = Bp1 + (kt) * 32; \
        S##00 = *(const f32x4*)p0; S##01 = *(const f32x4*)(p0 + 4); \
        S##10 = *(const f32x4*)p1; S##11 = *(const f32x4*)(p1 + 4); \
    } while (0)
#define BWRITE(S, buf) do { \
        s16x8 t0, t1; \
        t0[0] = f2bf(S##00[0]); t0[1] = f2bf(S##00[1]); t0[2] = f2bf(S##00[2]); t0[3] = f2bf(S##00[3]); \
        t0[4] = f2bf(S##01[0]); t0[5] = f2bf(S##01[1]); t0[6] = f2bf(S##01[2]); t0[7] = f2bf(S##01[3]); \
        t1[0] = f2bf(S##10[0]); t1[1] = f2bf(S##10[1]); t1[2] = f2bf(S##10[2]); t1[3] = f2bf(S##10[3]); \
        t1[4] = f2bf(S##11[0]); t1[5] = f2bf(S##11[1]); t1[6] = f2bf(S##11[2]); t1[7] = f2bf(S##11[3]); \
        *(s16x8*)&Bs[buf][sb0] = t0; *(s16x8*)&Bs[buf][sb1] = t1; \
    } while (0)
#define ASTAGE(buf, kt) do { \
        gld16(Ap0 + (kt) * 32, &As[buf][lb0]); \
        gld16(Ap1 + (kt) * 32, &As[buf][lb1]); \
    } while (0)
#define COMPUTE(buf) do { \
        s16x8 af[4], bfr[4]; \
        for (int mf = 0; mf < 4; ++mf) af[mf] = *(const s16x8*)&As[buf][aoff[mf]]; \
        for (int nf = 0; nf < 4; ++nf) bfr[nf] = *(const s16x8*)&Bs[buf][boff[nf]]; \
        for (int mf = 0; mf < 4; ++mf) \
            for (int nf = 0; nf < 4; ++nf) \
                acc[mf][nf] = __builtin_amdgcn_mfma_f32_16x16x32_bf16(af[mf], bfr[nf], acc[mf][nf], 0, 0, 0); \
    } while (0)

    int nk = Ksub >> 5;   // even, >= 2 at all call sites
    BLOAD(bA, 0);
    ASTAGE(0, 0);
    BWRITE(bA, 0);
    BLOAD(bB, 1);
    WAITBAR4;
    for (int kt = 0; kt < nk; kt += 2) {
        {
            if (kt + 1 < nk) ASTAGE(1, kt + 1);
            if (kt + 2 < nk) BLOAD(bA, kt + 2);
            COMPUTE(0);
            if (kt + 1 < nk) BWRITE(bB, 1);
            if (kt + 2 < nk) { WAITBAR4; } else { WAITBAR0; }
        }
        if (kt + 1 >= nk) break;
        {
            if (kt + 2 < nk) ASTAGE(0, kt + 2);
            if (kt + 3 < nk) BLOAD(bB, kt + 3);
            COMPUTE(1);
            if (kt + 2 < nk) BWRITE(bA, 0);
            if (kt + 3 < nk) { WAITBAR4; } else { WAITBAR0; }
        }
    }
#undef BLOAD
#undef BWRITE
#undef ASTAGE
#undef COMPUTE
    float* Cf = (float*)Cv;
    short* Cs = (short*)Cv;
#pragma unroll
    for (int mf = 0; mf < 4; ++mf) {
        int rbase = bm + wm + mf * 16 + lg * 4;
#pragma unroll
        for (int r = 0; r < 4; ++r) {
            int grow = rbase + r;
            if (grow < Mloc) {
                int crow = rl ? rl[grow] : grow;
                size_t cb = coff + (size_t)crow * N + bn + wn + lr;
                if (store_bf16) {
#pragma unroll
                    for (int nf = 0; nf < 4; ++nf) Cs[cb + nf * 16] = f2bf(acc[mf][nf][r]);
                } else {
#pragma unroll
                    for (int nf = 0; nf < 4; ++nf) Cf[cb + nf * 16] = acc[mf][nf][r];
                }
            }
        }
    }
}

// ---- RoPE; input qkv = 4 bf16 split-K slices [4][2048][1536]; out Qr*0.125, Kr, Vt[B,4,64,S] ----
__global__ __launch_bounds__(64) void rope_kernel(const short* __restrict__ qkv, short* __restrict__ Qr,
                                                  short* __restrict__ Kr, short* __restrict__ Vt) {
    int t = blockIdx.x;
    int b = t >> 10, s = t & 1023;
    int l = threadIdx.x;
    __shared__ float cs[32], sn[32], row[1536];
    float acc[24];
#pragma unroll
    for (int c = 0; c < 24; ++c) acc[c] = 0.f;
#pragma unroll
    for (int z = 0; z < 4; ++z) {
        const short* src = qkv + (size_t)z * 2048 * 1536 + (size_t)t * 1536 + l * 24;
#pragma unroll
        for (int c8 = 0; c8 < 3; ++c8) {
            s16x8 v8 = *(const s16x8*)(src + c8 * 8);
#pragma unroll
            for (int j = 0; j < 8; ++j) acc[c8 * 8 + j] += bf2f(v8[j]);
        }
    }
#pragma unroll
    for (int c = 0; c < 24; ++c) row[l * 24 + c] = acc[c];
    if (l < 32) {
        float fr = (float)t * exp2f(-(float)l * 0.41524101186f);
        cs[l] = cosf(fr); sn[l] = sinf(fr);
    }
    __syncthreads();
    int d = l;
    float c = cs[d & 31], sv = sn[d & 31];
#pragma unroll
    for (int h = 0; h < 16; ++h) {
        float x = row[h * 64 + d];
        float rot = (d < 32) ? -row[h * 64 + d + 32] : row[h * 64 + d - 32];
        Qr[((size_t)(b * 16 + h) * 1024 + s) * 64 + d] = f2bf((x * c + rot * sv) * 0.125f);
    }
#pragma unroll
    for (int h = 0; h < 4; ++h) {
        float x = row[1024 + h * 64 + d];
        float rot = (d < 32) ? -row[1024 + h * 64 + d + 32] : row[1024 + h * 64 + d - 32];
        Kr[((size_t)(b * 4 + h) * 1024 + s) * 64 + d] = f2bf(x * c + rot * sv);
        Vt[((size_t)(b * 4 + h) * 64 + d) * 1024 + s] = f2bf(row[1280 + h * 64 + d]);
    }
}

// ---------------- flash attention v2: paired q-tiles + K/V register prefetch ----------------
struct KV { s16x8 k[4]; s16x8 v[4]; };
__device__ __forceinline__ void kv_load(KV& r, const short* Kb, const short* Vb, int k0, int lr, int lg) {
    const short* K0 = Kb + (size_t)(k0 + lr) * 64 + lg * 8;
    const short* K1 = Kb + (size_t)(k0 + 16 + lr) * 64 + lg * 8;
    r.k[0] = *(const s16x8*)K0;
    r.k[1] = *(const s16x8*)(K0 + 32);
    r.k[2] = *(const s16x8*)K1;
    r.k[3] = *(const s16x8*)(K1 + 32);
#pragma unroll
    for (int dt = 0; dt < 4; ++dt)
        r.v[dt] = *(const s16x8*)(Vb + (size_t)(dt * 16 + lr) * 1024 + k0 + lg * 8);
}
__device__ __forceinline__ void chain_step(const KV& kv, s16x8 qf0, s16x8 qf1, f32x4* o,
                                           float& m, float& lsum, short* Pl,
                                           int lr, int lg, int k0, int qmask) {
    f32x4 z = {0.f, 0.f, 0.f, 0.f};
    f32x4 sc0 = z, sc1 = z;
    sc0 = __builtin_amdgcn_mfma_f32_16x16x32_bf16(kv.k[0], qf0, sc0, 0, 0, 0);
    sc0 = __builtin_amdgcn_mfma_f32_16x16x32_bf16(kv.k[1], qf1, sc0, 0, 0, 0);
    sc1 = __builtin_amdgcn_mfma_f32_16x16x32_bf16(kv.k[2], qf0, sc1, 0, 0, 0);
    sc1 = __builtin_amdgcn_mfma_f32_16x16x32_bf16(kv.k[3], qf1, sc1, 0, 0, 0);
#pragma unroll
    for (int r = 0; r < 4; ++r) {
        if (k0 + lg * 4 + r > qmask) sc0[r] = -1e30f;
        if (k0 + 16 + lg * 4 + r > qmask) sc1[r] = -1e30f;
    }
    float tm = fmaxf(fmaxf(fmaxf(sc0[0], sc0[1]), fmaxf(sc0[2], sc0[3])),
                     fmaxf(fmaxf(sc1[0], sc1[1]), fmaxf(sc1[2], sc1[3])));
    tm = fmaxf(tm, __shfl_xor(tm, 16));
    tm = fmaxf(tm, __shfl_xor(tm, 32));
    float newm = fmaxf(m, tm);
    float fac = __expf(m - newm);
    float p[8];
#pragma unroll
    for (int r = 0; r < 4; ++r) { p[r] = __expf(sc0[r] - newm); p[4 + r] = __expf(sc1[r] - newm); }
    float ts = ((p[0] + p[1]) + (p[2] + p[3])) + ((p[4] + p[5]) + (p[6] + p[7]));
    ts += __shfl_xor(ts, 16);
    ts += __shfl_xor(ts, 32);
    lsum = lsum * fac + ts;
    m = newm;
    s16x4 w0, w1;
#pragma unroll
    for (int r = 0; r < 4; ++r) { w0[r] = f2bf(p[r]); w1[r] = f2bf(p[4 + r]); }
    *(s16x4*)&Pl[lr * 40 + lg * 4] = w0;
    *(s16x4*)&Pl[lr * 40 + 16 + lg * 4] = w1;
    s16x8 pf = *(const s16x8*)&Pl[lr * 40 + lg * 8];
#pragma unroll
    for (int dt = 0; dt < 4; ++dt) {
        o[dt] *= fac;
        o[dt] = __builtin_amdgcn_mfma_f32_16x16x32_bf16(kv.v[dt], pf, o[dt], 0, 0, 0);
    }
}

__global__ __launch_bounds__(64) void attn_kernel(const short* __restrict__ Qr, const short* __restrict__ Kr,
                                                  const short* __restrict__ Vt, short* __restrict__ attn_out) {
    int p = blockIdx.x;
    int hb = blockIdx.y;
    int b = hb >> 4, h = hb & 15, kv = h >> 2;
    int l = threadIdx.x;
    int lr = l & 15, lg = l >> 4;
    int q0A = p * 16, q0B = (63 - p) * 16;
    __shared__ short PlA[16 * 40], PlB[16 * 40];
    const short* Qh = Qr + (size_t)(b * 16 + h) * 1024 * 64;
    s16x8 qA0 = *(const s16x8*)(Qh + (size_t)(q0A + lr) * 64 + lg * 8);
    s16x8 qA1 = *(const s16x8*)(Qh + (size_t)(q0A + lr) * 64 + 32 + lg * 8);
    s16x8 qB0 = *(const s16x8*)(Qh + (size_t)(q0B + lr) * 64 + lg * 8);
    s16x8 qB1 = *(const s16x8*)(Qh + (size_t)(q0B + lr) * 64 + 32 + lg * 8);
    const short* Kbase = Kr + (size_t)(b * 4 + kv) * 1024 * 64;
    const short* Vbase = Vt + (size_t)(b * 4 + kv) * 64 * 1024;

    f32x4 zero4 = {0.f, 0.f, 0.f, 0.f};
    f32x4 oA[4], oB[4];
#pragma unroll
    for (int dt = 0; dt < 4; ++dt) { oA[dt] = zero4; oB[dt] = zero4; }
    float mA = -1e30f, lsA = 0.f, mB = -1e30f, lsB = 0.f;
    int ntA = (q0A + 47) >> 5, ntB = (q0B + 47) >> 5;
    int qmA = q0A + lr, qmB = q0B + lr;
    const int BIG = 1 << 29;

    KV b0, b1;
    kv_load(b0, Kbase, Vbase, 0, lr, lg);
    for (int kt = 0; kt < ntB; kt += 2) {
        if (kt + 1 < ntB) kv_load(b1, Kbase, Vbase, (kt + 1) * 32, lr, lg);
        if (kt < ntA) chain_step(b0, qA0, qA1, oA, mA, lsA, PlA, lr, lg, kt * 32,
                                 (kt == ntA - 1) ? qmA : BIG);
        chain_step(b0, qB0, qB1, oB, mB, lsB, PlB, lr, lg, kt * 32,
                   (kt == ntB - 1) ? qmB : BIG);
        if (kt + 1 >= ntB) break;
        if (kt + 2 < ntB) kv_load(b0, Kbase, Vbase, (kt + 2) * 32, lr, lg);
        if (kt + 1 < ntA) chain_step(b1, qA0, qA1, oA, mA, lsA, PlA, lr, lg, (kt + 1) * 32,
                                     (kt + 1 == ntA - 1) ? qmA : BIG);
        chain_step(b1, qB0, qB1, oB, mB, lsB, PlB, lr, lg, (kt + 1) * 32,
                   (kt + 1 == ntB - 1) ? qmB : BIG);
    }
    float invA = 1.f / lsA, invB = 1.f / lsB;
    short* oa = attn_out + ((size_t)(b * 1024 + q0A + lr)) * 1024 + h * 64;
    short* ob = attn_out + ((size_t)(b * 1024 + q0B + lr)) * 1024 + h * 64;
#pragma unroll
    for (int dt = 0; dt < 4; ++dt)
#pragma unroll
        for (int r = 0; r < 4; ++r) {
            oa[dt * 16 + lg * 4 + r] = f2bf(oA[dt][r] * invA);
            ob[dt * 16 + lg * 4 + r] = f2bf(oB[dt][r] * invB);
        }
}

// ---------------- router R1: logits + top-k per token (no atomics) ----------------
__global__ __launch_bounds__(256) void router_topk_kernel(const float* __restrict__ x32, const float* __restrict__ gw,
                                                          const float* __restrict__ eb, float* __restrict__ tw,
                                                          int* __restrict__ tidx) {
    int t = blockIdx.x * 4 + (threadIdx.x >> 6);
    int l = threadIdx.x & 63;
    const float* x = x32 + (size_t)t * 1024;
    f32x4 xv[4];
#pragma unroll
    for (int j = 0; j < 4; ++j) xv[j] = *(const f32x4*)(x + j * 256 + l * 4);
    float acc[16];
#pragma unroll
    for (int e = 0; e < 16; ++e) {
        float a = 0.f;
#pragma unroll
        for (int j = 0; j < 4; ++j) {
            f32x4 g = *(const f32x4*)(gw + (size_t)e * 1024 + j * 256 + l * 4);
            a += xv[j][0]*g[0] + xv[j][1]*g[1] + xv[j][2]*g[2] + xv[j][3]*g[3];
        }
        acc[e] = a;
    }
#pragma unroll
    for (int e = 0; e < 16; ++e) {
#pragma unroll
        for (int o = 1; o < 64; o <<= 1) acc[e] += __shfl_xor(acc[e], o);
    }
    if (l == 0) {
        float score[16], sfc[16];
#pragma unroll
        for (int e = 0; e < 16; ++e) {
            score[e] = 1.f / (1.f + __expf(-acc[e]));
            sfc[e] = score[e] + eb[e];
        }
        float gs[4];
#pragma unroll
        for (int g = 0; g < 4; ++g)
            gs[g] = fmaxf(fmaxf(sfc[4 * g], sfc[4 * g + 1]), fmaxf(sfc[4 * g + 2], sfc[4 * g + 3]));
        int g1 = 0;
        for (int g = 1; g < 4; ++g) if (gs[g] > gs[g1]) g1 = g;
        int g2 = -1;
        for (int g = 0; g < 4; ++g) {
            if (g == g1) continue;
            if (g2 < 0 || gs[g] > gs[g2]) g2 = g;
        }
        float masked[16];
#pragma unroll
        for (int e = 0; e < 16; ++e) {
            int g = e >> 2;
            masked[e] = (g == g1 || g == g2) ? sfc[e] : 0.0f;
        }
        float tot = 1e-20f;
        int idx[4]; float wv[4];
        for (int k = 0; k < 4; ++k) {
            int bi = 0;
            float bv = -1e30f;
            for (int e2 = 0; e2 < 16; ++e2)
                if (masked[e2] > bv) { bv = masked[e2]; bi = e2; }
            idx[k] = bi;
            wv[k] = score[bi];
            masked[bi] = -1e30f;
            tot += wv[k];
        }
        for (int k = 0; k < 4; ++k) {
            tw[t * 4 + k] = wv[k] / tot * 2.5f;
            tidx[t * 4 + k] = idx[k];
        }
    }
}

// ---------------- router R2: per-expert ordered compaction (1 wave per expert) ----------------
__global__ __launch_bounds__(64) void router_lists_kernel(const int* __restrict__ tidx, int* __restrict__ counts,
                                                          int* __restrict__ lists) {
    int e = blockIdx.x;
    int l = threadIdx.x;
    int base = 0;
    for (int it = 0; it < 128; ++it) {
        int p = it * 64 + l;
        bool match = (tidx[p] == e);
        unsigned long long mask = __ballot(match);
        int pos = __popcll(mask & ((1ull << l) - 1ull));
        if (match) lists[e * 2048 + base + pos] = p;
        base += __popcll(mask);
    }
    if (l == 0) counts[e] = base;
}

// ---- build (expert, mblock) work list: plan[0]=count, plan[1+i] = e | (m<<5) ----
__global__ void plan_kernel(const int* __restrict__ counts, int* __restrict__ plan) {
    if (threadIdx.x == 0) {
        int n = 0;
        for (int e = 0; e < 16; ++e) {
            int nb = (counts[e] + 127) >> 7;
            for (int m2 = 0; m2 < nb; ++m2) plan[1 + n++] = e | (m2 << 5);
        }
        plan[0] = n;
    }
}

// ---- silu-mul routed: gu single bf16 slice [8192][1024] -> hid[p][512] bf16 ----
__global__ __launch_bounds__(128) void silu_routed_kernel(const short* __restrict__ gu, short* __restrict__ hid) {
    int pr = blockIdx.x;
    int j = threadIdx.x * 4;
    const short* base = gu + (size_t)pr * 1024;
    s16x4 gz = *(const s16x4*)(base + j);
    s16x4 uz = *(const s16x4*)(base + 512 + j);
    s16x4 o;
#pragma unroll
    for (int k = 0; k < 4; ++k) {
        float g = bf2f(gz[k]);
        o[k] = f2bf(g / (1.f + __expf(-g)) * bf2f(uz[k]));
    }
    *(s16x4*)(hid + (size_t)pr * 512 + j) = o;
}

// ---- silu-mul shared: sgsu 2 bf16 slices [2][2048][2048] -> shhid[t][1024] bf16 ----
__global__ __launch_bounds__(256) void silu_shared_kernel(const short* __restrict__ gu, short* __restrict__ h) {
    int t = blockIdx.x;
    int j = threadIdx.x * 4;
    float g[4] = {0.f, 0.f, 0.f, 0.f}, u2[4] = {0.f, 0.f, 0.f, 0.f};
#pragma unroll
    for (int z = 0; z < 2; ++z) {
        const short* base = gu + (size_t)z * 2048 * 2048 + (size_t)t * 2048;
        s16x4 gz = *(const s16x4*)(base + j);
        s16x4 uz = *(const s16x4*)(base + 1024 + j);
#pragma unroll
        for (int k = 0; k < 4; ++k) { g[k] += bf2f(gz[k]); u2[k] += bf2f(uz[k]); }
    }
    s16x4 o;
#pragma unroll
    for (int k = 0; k < 4; ++k) o[k] = f2bf(g[k] / (1.f + __expf(-g[k])) * u2[k]);
    *(s16x4*)(h + (size_t)t * 1024 + j) = o;
}

// ---- combine: out = res2 + sum_z sd[z] + sum_s w_s * down[t*4+s] ----
__global__ __launch_bounds__(256) void combine_kernel(const float* __restrict__ res2, const short* __restrict__ sdp,
                                                      const short* __restrict__ slots, const float* __restrict__ tw,
                                                      float* __restrict__ out) {
    int t = blockIdx.x;
    int i = threadIdx.x;
    f32x4 acc = ((const f32x4*)(res2 + (size_t)t * 1024))[i];
#pragma unroll
    for (int z = 0; z < 4; ++z) {
        s16x4 d = *(const s16x4*)(sdp + (size_t)z * 2048 * 1024 + (size_t)t * 1024 + i * 4);
#pragma unroll
        for (int j = 0; j < 4; ++j) acc[j] += bf2f(d[j]);
    }
#pragma unroll
    for (int s = 0; s < 4; ++s) {
        float w = tw[t * 4 + s];
        s16x4 d = ((const s16x4*)(slots + (size_t)(t * 4 + s) * 1024))[i];
#pragma unroll
        for (int j = 0; j < 4; ++j) acc[j] += bf2f(d[j]) * w;
    }
    ((f32x4*)(out + (size_t)t * 1024))[i] = acc;
}

extern "C" void kernel_launch(void* const* d_in, const int* in_sizes, int n_in,
                              void* d_out, int out_size, void* d_ws, size_t ws_size,
                              hipStream_t stream) {
    const float* hidden = (const float*)d_in[0];
    const float* ln1 = (const float*)d_in[2];
    const float* ln2 = (const float*)d_in[3];
    const float* qw = (const float*)d_in[4];
    const float* kw = (const float*)d_in[5];
    const float* vw = (const float*)d_in[6];
    const float* ow = (const float*)d_in[7];
    const float* gatew = (const float*)d_in[8];
    const float* ebias = (const float*)d_in[9];
    const float* wgu = (const float*)d_in[10];
    const float* wd = (const float*)d_in[11];
    const float* sgw = (const float*)d_in[12];
    const float* suw = (const float*)d_in[13];
    const float* sdw = (const float*)d_in[14];
    float* out = (float*)d_out;

    char* base = (char*)d_ws;
    size_t off = 0;
    auto alloc = [&](size_t bytes) -> char* {
        char* r = base + off;
        off += (bytes + 255) & ~(size_t)255;
        return r;
    };
    const size_t MB = 1u << 20;

    // ---- persistent weights (bf16: qkv, sgsu, o, sd)
    short* wqkv_b = (short*)alloc((size_t)1536 * 1024 * 2);
    short* wsgsu_b= (short*)alloc((size_t)2048 * 1024 * 2);
    short* wo_b   = (short*)alloc((size_t)1024 * 1024 * 2);
    short* wsd_b  = (short*)alloc((size_t)1024 * 1024 * 2);
    // ---- persistent activations / routing
    float* res2 = (float*)alloc((size_t)2048 * 1024 * 4);
    short* xf   = (short*)alloc((size_t)2048 * 1024 * 2);
    float* topkw = (float*)alloc(2048 * 4 * 4);
    int* tidx   = (int*)alloc(8192 * 4);
    int* counts = (int*)alloc(64);
    int* lists  = (int*)alloc(16 * 2048 * 4);
    int* plan   = (int*)alloc(512);
    short* shhid = (short*)alloc((size_t)2048 * 1024 * 2);
    short* hid   = (short*)alloc((size_t)8192 * 512 * 2);

    // ---- overlay region (50 MiB), sequential phases
    char* ov = alloc(50 * MB);
    short* xn1       = (short*)(ov);                 // 4 MB
    short* qkv_part  = (short*)(ov + 4 * MB);        // 4 slices x 6 MB = 24 MB
    short* Qr        = (short*)(ov);                 // 4 MB (xn1 dead)
    short* Kr        = (short*)(ov + 28 * MB);       // 1 MB
    short* Vt        = (short*)(ov + 29 * MB);       // 1 MB
    short* attn_out  = (short*)(ov + 30 * MB);       // 4 MB
    short* attnproj_part = (short*)(ov + 34 * MB);   // 4 slices x 4 MB = 16 MB
    float* xf32      = (float*)(ov);                 // 8 MB (Qr dead after attn)
    short* upbuf     = (short*)(ov);                 // 16 MB: sgsu 2x8MB, then gu 1x16MB
    short* down_slot = (short*)(ov + 16 * MB);       // 16 MB
    short* sd_part   = (short*)(ov + 32 * MB);       // 4 slices x 4 MB = 16 MB

    // ---- weight conversion (qkv + sgsu + o + sd)
    cvt_small_kernel<<<2816, 256, 0, stream>>>(qw, kw, vw, sgw, suw, ow, sdw,
                                               wqkv_b, wsgsu_b, wo_b, wsd_b);

    // ---- attention block
    rmsnorm_kernel<<<2048, 256, 0, stream>>>(hidden, ln1, xn1);
    gemm2_kernel<<<dim3(16, 12, 4), 256, 0, stream>>>(xn1, wqkv_b, qkv_part, 2048, 1536, 1024, 256,
                                                      2048LL * 1536, 1);
    rope_kernel<<<2048, 64, 0, stream>>>(qkv_part, Qr, Kr, Vt);
    attn_kernel<<<dim3(32, 32, 1), 64, 0, stream>>>(Qr, Kr, Vt, attn_out);
    gemm2_kernel<<<dim3(16, 8, 4), 256, 0, stream>>>(attn_out, wo_b, attnproj_part, 2048, 1024, 1024, 256,
                                                     2048LL * 1024, 1);
    addnorm_kernel<<<2048, 256, 0, stream>>>(hidden, attnproj_part, ln2, res2, xf, xf32);

    // ---- router (atomic-free) + plan
    router_topk_kernel<<<512, 256, 0, stream>>>(xf32, gatew, ebias, topkw, tidx);
    router_lists_kernel<<<16, 64, 0, stream>>>(tidx, counts, lists);
    plan_kernel<<<1, 64, 0, stream>>>(counts, plan);

    // ---- shared expert up (sg|su fused bf16 B, split-K 2) + silu
    gemm2_kernel<<<dim3(16, 16, 2), 256, 0, stream>>>(xf, wsgsu_b, upbuf, 2048, 2048, 1024, 512,
                                                      2048LL * 2048, 1);
    silu_shared_kernel<<<2048, 256, 0, stream>>>(upbuf, shhid);

    // ---- routed experts up (f32 B direct, plan-mode, no split-K) + silu
    gemm3_kernel<<<dim3(8, 80, 1), 256, 0, stream>>>(xf, wgu, upbuf, 0, 1024, 1024, 1024,
                                                     0LL, counts, lists, plan, 2, 1);
    silu_routed_kernel<<<8192, 128, 0, stream>>>(upbuf, hid);

    // ---- down projections
    gemm3_kernel<<<dim3(8, 80, 1), 256, 0, stream>>>(hid, wd, down_slot, 0, 1024, 512, 512,
                                                     0LL, counts, lists, plan, 0, 1);
    gemm2_kernel<<<dim3(16, 8, 4), 256, 0, stream>>>(shhid, wsd_b, sd_part, 2048, 1024, 1024, 256,
                                                     2048LL * 1024, 1);

    // ---- combine
    combine_kernel<<<2048, 256, 0, stream>>>(res2, sd_part, down_slot, topkw, out);

    (void)in_sizes; (void)n_in; (void)out_size; (void)ws_size;
}